// Round 2
// baseline (9232.649 us; speedup 1.0000x reference)
//
#include <hip/hip_runtime.h>
#include <hip/hip_bf16.h>
#include <math.h>

#define BB 64
#define LL 64
#define EE 512
#define HH 512
#define G4 2048
#define VT 32000
#define RT 4096  // LL*BB

typedef unsigned short u16;
typedef __attribute__((ext_vector_type(8))) unsigned short ushort8;
typedef __attribute__((ext_vector_type(8))) short bf16x8;
typedef __attribute__((ext_vector_type(4))) float f32x4;

// ---------------- static device scratch (~180 MB) ----------------
__device__ u16   gW2T[(size_t)VT * 1024];   // h2o_W^T  (VT x 1024) bf16
__device__ u16   gEncWxT[G4 * EE];          // enc_Wx^T (2048 x 512)
__device__ u16   gEncWhT[G4 * HH];
__device__ u16   gAttWhT[HH * HH];
__device__ u16   gAttWsT[HH * HH];
__device__ u16   gDecWxTe[G4 * EE];         // dec_Wx rows 0..511 ^T
__device__ u16   gDecWxTc[G4 * HH];         // dec_Wx rows 512..1023 ^T
__device__ u16   gDecWhT[G4 * HH];
__device__ u16   gSrcEmb[RT * EE];          // bf16 gathered src emb, row r=t*64+b
__device__ u16   gTgtEmb[RT * EE];
__device__ float gXWxE[(size_t)RT * G4];    // src_emb @ enc_Wx
__device__ float gXWxD[(size_t)RT * G4];    // tgt_emb @ dec_Wx[:512]
__device__ float gEncH[(size_t)RT * HH];    // enc_hiddens fp32, row r=t*64+b
__device__ u16   gEncHb[(size_t)RT * HH];   // enc_hiddens bf16
__device__ float gEncT[(size_t)RT * HH];    // enc_hiddens @ att_Wh
__device__ u16   gHcat[(size_t)RT * 1024];  // [h | ctx] bf16 per dec step
__device__ float gDecT[BB * HH];            // h_prev @ att_Ws (per step)
__device__ float gC[BB * HH];               // LSTM cell state fp32
__device__ u16   gH0[BB * HH];              // zero bf16 h for t=0

__device__ inline u16 f2b(float f) {
    union { float f; unsigned u; } v{f};
    unsigned r = v.u + 0x7fffu + ((v.u >> 16) & 1u);
    return (u16)(r >> 16);
}
__device__ inline float sigm(float x) { return 1.f / (1.f + expf(-x)); }

// ---------------- transpose fp32 (R x C) -> bf16 (C x R) ----------------
__device__ inline u16* bf16sel(int s) {
    switch (s) {
        case 0: return gW2T;    case 1: return gEncWxT; case 2: return gEncWhT;
        case 3: return gAttWhT; case 4: return gAttWsT; case 5: return gDecWxTe;
        case 6: return gDecWxTc; default: return gDecWhT;
    }
}

__global__ __launch_bounds__(256) void k_transpose(const float* __restrict__ in, int R, int C, int sel) {
    __shared__ float tile[32][33];
    int tx = threadIdx.x & 31, ty0 = threadIdx.x >> 5;
    int c0 = blockIdx.x * 32, r0 = blockIdx.y * 32;
#pragma unroll
    for (int k = 0; k < 4; k++) {
        int ty = ty0 + k * 8;
        tile[ty][tx] = in[(size_t)(r0 + ty) * C + c0 + tx];
    }
    __syncthreads();
    u16* out = bf16sel(sel);
#pragma unroll
    for (int k = 0; k < 4; k++) {
        int ty = ty0 + k * 8;
        out[(size_t)(c0 + ty) * R + r0 + tx] = f2b(tile[tx][ty]);
    }
}

// ---------------- embedding gather -> bf16, row r = t*64+b ----------------
__global__ __launch_bounds__(256) void k_gather(const int* __restrict__ tok, const float* __restrict__ tab, int sel) {
    int r = blockIdx.x;
    int b = r & 63, t = r >> 6;
    int token = tok[b * LL + t];
    u16* dst = (sel == 0) ? gSrcEmb : gTgtEmb;
    const float* srow = tab + (size_t)token * EE;
    for (int e = threadIdx.x; e < EE; e += 256)
        dst[(size_t)r * EE + e] = f2b(srow[e]);
}

__global__ __launch_bounds__(256) void k_zero() {
    int i = blockIdx.x * 256 + threadIdx.x;  // 128 blocks * 256 = 32768
    gC[i] = 0.f;
    gH0[i] = 0;
}

// ---------------- generic bf16 MFMA GEMM: C(MxN) = A(MxK) * B^T(NxK) ----------------
// epi 0: Cg[row*N+col] = v ; epi 1: out[((row%64)*64 + row/64)*N + col] = v + bias[col]
__global__ __launch_bounds__(256) void k_gemm(int selA, int lda, int selB, int ldb,
                                              int M, int N, int K, int epi,
                                              const float* __restrict__ bias,
                                              float* __restrict__ outPtr, int selOut) {
    __shared__ u16 sA[128 * 72];
    __shared__ u16 sB[128 * 72];
    const u16* Ag;
    switch (selA) { case 0: Ag = gSrcEmb; break; case 1: Ag = gTgtEmb; break; case 2: Ag = gEncHb; break; default: Ag = gHcat; }
    const u16* Bg;
    switch (selB) { case 0: Bg = gEncWxT; break; case 1: Bg = gDecWxTe; break; case 2: Bg = gAttWhT; break; default: Bg = gW2T; }
    float* Cg;
    if (selOut == 0) Cg = gXWxE; else if (selOut == 1) Cg = gXWxD; else if (selOut == 2) Cg = gEncT; else Cg = outPtr;

    int tid = threadIdx.x, l = tid & 63, wid = tid >> 6, wr = wid >> 1, wc = wid & 1;
    int ar = l & 15, ak = (l >> 4) * 8;
    int rowM = blockIdx.y * 128, colN = blockIdx.x * 128;
    f32x4 acc[4][4];
#pragma unroll
    for (int m = 0; m < 4; m++)
#pragma unroll
        for (int n = 0; n < 4; n++) acc[m][n] = (f32x4){0.f, 0.f, 0.f, 0.f};

    for (int k0 = 0; k0 < K; k0 += 64) {
        // stage full 128x64 tiles: 1024 chunks of 8 elems, 4 per thread
#pragma unroll
        for (int it = 0; it < 4; it++) {
            int idx = it * 256 + tid;
            int row = idx >> 3, cc = idx & 7;
            *(ushort8*)(sA + row * 72 + cc * 8) =
                *(const ushort8*)(Ag + (size_t)(rowM + row) * lda + k0 + cc * 8);
            *(ushort8*)(sB + row * 72 + cc * 8) =
                *(const ushort8*)(Bg + (size_t)(colN + row) * ldb + k0 + cc * 8);
        }
        __syncthreads();
#pragma unroll
        for (int ks = 0; ks < 2; ks++) {
            bf16x8 a[4], b[4];
#pragma unroll
            for (int m = 0; m < 4; m++) a[m] = *(const bf16x8*)(sA + (wr * 64 + m * 16 + ar) * 72 + ks * 32 + ak);
#pragma unroll
            for (int n = 0; n < 4; n++) b[n] = *(const bf16x8*)(sB + (wc * 64 + n * 16 + ar) * 72 + ks * 32 + ak);
#pragma unroll
            for (int m = 0; m < 4; m++)
#pragma unroll
                for (int n = 0; n < 4; n++)
                    acc[m][n] = __builtin_amdgcn_mfma_f32_16x16x32_bf16(a[m], b[n], acc[m][n], 0, 0, 0);
        }
        __syncthreads();
    }
    int rb = (l >> 4) * 4;
#pragma unroll
    for (int m = 0; m < 4; m++)
#pragma unroll
        for (int n = 0; n < 4; n++)
#pragma unroll
            for (int ri = 0; ri < 4; ri++) {
                int row = rowM + wr * 64 + m * 16 + rb + ri;
                int col = colN + wc * 64 + n * 16 + ar;
                float v = acc[m][n][ri];
                if (epi == 0) Cg[(size_t)row * N + col] = v;
                else Cg[(size_t)((row & 63) * 64 + (row >> 6)) * N + col] = v + bias[col];
            }
}

// ---------------- encoder LSTM step: z = XWxE[t] + h@Wh + b -> gates ----------------
// 8 blocks x 256 threads; wave j=bx*4+wid owns hcols j*16..j*16+15 for all 4 gates.
__global__ __launch_bounds__(256) void k_enc_step(int t, const float* __restrict__ eb) {
    int tid = threadIdx.x, l = tid & 63, wid = tid >> 6;
    int j = blockIdx.x * 4 + wid;
    const u16* hp = (t == 0) ? gH0 : (gEncHb + (size_t)(t - 1) * BB * HH);
    int ar = l & 15, ak = (l >> 4) * 8;
    f32x4 acc[4][4];
#pragma unroll
    for (int m = 0; m < 4; m++)
#pragma unroll
        for (int g = 0; g < 4; g++) acc[m][g] = (f32x4){0.f, 0.f, 0.f, 0.f};
    for (int kk = 0; kk < 16; kk++) {
        int k = kk * 32 + ak;
        bf16x8 a[4], b[4];
#pragma unroll
        for (int m = 0; m < 4; m++) a[m] = *(const bf16x8*)(hp + (size_t)(m * 16 + ar) * HH + k);
#pragma unroll
        for (int g = 0; g < 4; g++) b[g] = *(const bf16x8*)(gEncWhT + (size_t)(g * 512 + j * 16 + ar) * HH + k);
#pragma unroll
        for (int m = 0; m < 4; m++)
#pragma unroll
            for (int g = 0; g < 4; g++)
                acc[m][g] = __builtin_amdgcn_mfma_f32_16x16x32_bf16(a[m], b[g], acc[m][g], 0, 0, 0);
    }
    int hcol = j * 16 + ar, rb = (l >> 4) * 4;
#pragma unroll
    for (int m = 0; m < 4; m++)
#pragma unroll
        for (int ri = 0; ri < 4; ri++) {
            int row = m * 16 + rb + ri;
            int rr = t * BB + row;
            const float* xw = &gXWxE[(size_t)rr * G4];
            float zi = acc[m][0][ri] + xw[hcol] + eb[hcol];
            float zf = acc[m][1][ri] + xw[512 + hcol] + eb[512 + hcol];
            float zg = acc[m][2][ri] + xw[1024 + hcol] + eb[1024 + hcol];
            float zo = acc[m][3][ri] + xw[1536 + hcol] + eb[1536 + hcol];
            float co = gC[row * HH + hcol];
            float cn = sigm(zf) * co + sigm(zi) * tanhf(zg);
            float hn = sigm(zo) * tanhf(cn);
            gC[row * HH + hcol] = cn;
            gEncH[(size_t)rr * HH + hcol] = hn;
            gEncHb[(size_t)rr * HH + hcol] = f2b(hn);
        }
}

// ---------------- decoder: dec_t = h_prev @ att_Ws (64x512, K=512) ----------------
__global__ __launch_bounds__(256) void k_dect(int t) {
    int tid = threadIdx.x, l = tid & 63, wid = tid >> 6;
    int j = blockIdx.x * 4 + wid;  // 0..31
    const u16* hp; int hlda;
    if (t == 0) { hp = gEncHb + (size_t)63 * BB * HH; hlda = 512; }
    else        { hp = gHcat + (size_t)(t - 1) * BB * 1024; hlda = 1024; }
    int ar = l & 15, ak = (l >> 4) * 8;
    f32x4 acc[4];
#pragma unroll
    for (int m = 0; m < 4; m++) acc[m] = (f32x4){0.f, 0.f, 0.f, 0.f};
    for (int kk = 0; kk < 16; kk++) {
        int k = kk * 32 + ak;
        bf16x8 bfr = *(const bf16x8*)(gAttWsT + (size_t)(j * 16 + ar) * HH + k);
#pragma unroll
        for (int m = 0; m < 4; m++) {
            bf16x8 afr = *(const bf16x8*)(hp + (size_t)(m * 16 + ar) * hlda + k);
            acc[m] = __builtin_amdgcn_mfma_f32_16x16x32_bf16(afr, bfr, acc[m], 0, 0, 0);
        }
    }
    int col = j * 16 + ar, rb = (l >> 4) * 4;
#pragma unroll
    for (int m = 0; m < 4; m++)
#pragma unroll
        for (int ri = 0; ri < 4; ri++)
            gDecT[(m * 16 + rb + ri) * HH + col] = acc[m][ri];
}

// ---------------- attention: energy/softmax/context, one WG per batch row ----------------
__global__ __launch_bounds__(256) void k_attn(int t, const float* __restrict__ av) {
    int b = blockIdx.x, tid = threadIdx.x;
    __shared__ float dt[512];
    __shared__ float att[64];
    __shared__ float red[256];
    dt[tid] = gDecT[b * HH + tid];
    dt[tid + 256] = gDecT[b * HH + tid + 256];
    __syncthreads();
    // energy: s = tid>>2 (0..63), q = tid&3 sums 128 h each
    int s = tid >> 2, q = tid & 3;
    const float* et = gEncT + (size_t)(s * BB + b) * HH;
    float p = 0.f;
    for (int i = 0; i < 128; i++) {
        int h = i * 4 + q;
        p += tanhf(et[h] + dt[h]) * av[h];
    }
    red[tid] = p;
    __syncthreads();
    if (tid < 64) att[tid] = red[tid * 4] + red[tid * 4 + 1] + red[tid * 4 + 2] + red[tid * 4 + 3];
    __syncthreads();
    if (tid < 64) {
        float v = att[tid];
        float m = v;
        for (int o = 32; o; o >>= 1) m = fmaxf(m, __shfl_xor(m, o));
        float e = expf(v - m);
        float ssum = e;
        for (int o = 32; o; o >>= 1) ssum += __shfl_xor(ssum, o);
        att[tid] = e / ssum;
    }
    __syncthreads();
    for (int h = tid; h < HH; h += 256) {
        float c = 0.f;
        for (int s2 = 0; s2 < 64; s2++)
            c += att[s2] * gEncH[(size_t)(s2 * BB + b) * HH + h];
        gHcat[(size_t)(t * BB + b) * 1024 + 512 + h] = f2b(c);
    }
}

// ---------------- decoder LSTM step ----------------
__global__ __launch_bounds__(256) void k_dec_step(int t, const float* __restrict__ db) {
    int tid = threadIdx.x, l = tid & 63, wid = tid >> 6;
    int j = blockIdx.x * 4 + wid;
    const u16* hp; int hlda;
    if (t == 0) { hp = gEncHb + (size_t)63 * BB * HH; hlda = 512; }
    else        { hp = gHcat + (size_t)(t - 1) * BB * 1024; hlda = 1024; }
    const u16* cx = gHcat + (size_t)t * BB * 1024 + 512;  // lda 1024
    int ar = l & 15, ak = (l >> 4) * 8;
    f32x4 acc[4][4];
#pragma unroll
    for (int m = 0; m < 4; m++)
#pragma unroll
        for (int g = 0; g < 4; g++) acc[m][g] = (f32x4){0.f, 0.f, 0.f, 0.f};
    // segment 1: ctx @ dec_Wx[512:]
    for (int kk = 0; kk < 16; kk++) {
        int k = kk * 32 + ak;
        bf16x8 a[4], b[4];
#pragma unroll
        for (int m = 0; m < 4; m++) a[m] = *(const bf16x8*)(cx + (size_t)(m * 16 + ar) * 1024 + k);
#pragma unroll
        for (int g = 0; g < 4; g++) b[g] = *(const bf16x8*)(gDecWxTc + (size_t)(g * 512 + j * 16 + ar) * HH + k);
#pragma unroll
        for (int m = 0; m < 4; m++)
#pragma unroll
            for (int g = 0; g < 4; g++)
                acc[m][g] = __builtin_amdgcn_mfma_f32_16x16x32_bf16(a[m], b[g], acc[m][g], 0, 0, 0);
    }
    // segment 2: h_prev @ dec_Wh
    for (int kk = 0; kk < 16; kk++) {
        int k = kk * 32 + ak;
        bf16x8 a[4], b[4];
#pragma unroll
        for (int m = 0; m < 4; m++) a[m] = *(const bf16x8*)(hp + (size_t)(m * 16 + ar) * hlda + k);
#pragma unroll
        for (int g = 0; g < 4; g++) b[g] = *(const bf16x8*)(gDecWhT + (size_t)(g * 512 + j * 16 + ar) * HH + k);
#pragma unroll
        for (int m = 0; m < 4; m++)
#pragma unroll
            for (int g = 0; g < 4; g++)
                acc[m][g] = __builtin_amdgcn_mfma_f32_16x16x32_bf16(a[m], b[g], acc[m][g], 0, 0, 0);
    }
    int hcol = j * 16 + ar, rb = (l >> 4) * 4;
#pragma unroll
    for (int m = 0; m < 4; m++)
#pragma unroll
        for (int ri = 0; ri < 4; ri++) {
            int row = m * 16 + rb + ri;
            int rr = t * BB + row;
            const float* xw = &gXWxD[(size_t)rr * G4];
            float zi = acc[m][0][ri] + xw[hcol] + db[hcol];
            float zf = acc[m][1][ri] + xw[512 + hcol] + db[512 + hcol];
            float zg = acc[m][2][ri] + xw[1024 + hcol] + db[1024 + hcol];
            float zo = acc[m][3][ri] + xw[1536 + hcol] + db[1536 + hcol];
            float co = gC[row * HH + hcol];
            float cn = sigm(zf) * co + sigm(zi) * tanhf(zg);
            float hn = sigm(zo) * tanhf(cn);
            gC[row * HH + hcol] = cn;
            gHcat[(size_t)rr * 1024 + hcol] = f2b(hn);
        }
}

// ---------------- log-softmax in place over rows of 32000 ----------------
__global__ __launch_bounds__(256) void k_lsm(float* __restrict__ out) {
    int row = blockIdx.x, tid = threadIdx.x;
    float* p = out + (size_t)row * VT;
    __shared__ float red[4];
    float m = -1e30f;
    for (int i = tid; i < VT; i += 256) m = fmaxf(m, p[i]);
    for (int o = 32; o; o >>= 1) m = fmaxf(m, __shfl_xor(m, o));
    if ((tid & 63) == 0) red[tid >> 6] = m;
    __syncthreads();
    m = fmaxf(fmaxf(red[0], red[1]), fmaxf(red[2], red[3]));
    __syncthreads();
    float s = 0.f;
    for (int i = tid; i < VT; i += 256) s += expf(p[i] - m);
    for (int o = 32; o; o >>= 1) s += __shfl_xor(s, o);
    if ((tid & 63) == 0) red[tid >> 6] = s;
    __syncthreads();
    s = red[0] + red[1] + red[2] + red[3];
    float lse = m + logf(s);
    for (int i = tid; i < VT; i += 256) p[i] -= lse;
}

extern "C" void kernel_launch(void* const* d_in, const int* in_sizes, int n_in,
                              void* d_out, int out_size, void* d_ws, size_t ws_size,
                              hipStream_t stream) {
    const int*   src       = (const int*)d_in[0];
    const int*   tgt       = (const int*)d_in[1];
    const float* src_embed = (const float*)d_in[2];
    const float* enc_Wx    = (const float*)d_in[3];
    const float* enc_Wh    = (const float*)d_in[4];
    const float* enc_b     = (const float*)d_in[5];
    const float* tgt_embed = (const float*)d_in[6];
    const float* att_Wh    = (const float*)d_in[7];
    const float* att_Ws    = (const float*)d_in[8];
    const float* att_v     = (const float*)d_in[9];
    const float* dec_Wx    = (const float*)d_in[10];
    const float* dec_Wh    = (const float*)d_in[11];
    const float* dec_b     = (const float*)d_in[12];
    const float* h2o_W     = (const float*)d_in[13];
    const float* h2o_b     = (const float*)d_in[14];
    float* out = (float*)d_out;
    dim3 blk(256);

    // weight transposes -> bf16
    k_transpose<<<dim3(VT / 32, 1024 / 32), blk, 0, stream>>>(h2o_W, 1024, VT, 0);
    k_transpose<<<dim3(G4 / 32, EE / 32), blk, 0, stream>>>(enc_Wx, EE, G4, 1);
    k_transpose<<<dim3(G4 / 32, HH / 32), blk, 0, stream>>>(enc_Wh, HH, G4, 2);
    k_transpose<<<dim3(HH / 32, HH / 32), blk, 0, stream>>>(att_Wh, HH, HH, 3);
    k_transpose<<<dim3(HH / 32, HH / 32), blk, 0, stream>>>(att_Ws, HH, HH, 4);
    k_transpose<<<dim3(G4 / 32, EE / 32), blk, 0, stream>>>(dec_Wx, EE, G4, 5);
    k_transpose<<<dim3(G4 / 32, HH / 32), blk, 0, stream>>>(dec_Wx + (size_t)512 * G4, HH, G4, 6);
    k_transpose<<<dim3(G4 / 32, HH / 32), blk, 0, stream>>>(dec_Wh, HH, G4, 7);
    // embedding gathers
    k_gather<<<RT, blk, 0, stream>>>(src, src_embed, 0);
    k_gather<<<RT, blk, 0, stream>>>(tgt, tgt_embed, 1);
    k_zero<<<128, blk, 0, stream>>>();
    // hoisted input GEMMs
    k_gemm<<<dim3(G4 / 128, RT / 128), blk, 0, stream>>>(0, 512, 0, 512, RT, G4, 512, 0, nullptr, nullptr, 0);
    k_gemm<<<dim3(G4 / 128, RT / 128), blk, 0, stream>>>(1, 512, 1, 512, RT, G4, 512, 0, nullptr, nullptr, 1);
    // encoder recurrence
    for (int t = 0; t < LL; t++)
        k_enc_step<<<8, blk, 0, stream>>>(t, enc_b);
    // enc_t = enc_hiddens @ att_Wh
    k_gemm<<<dim3(HH / 128, RT / 128), blk, 0, stream>>>(2, 512, 2, 512, RT, HH, 512, 0, nullptr, nullptr, 2);
    // decoder recurrence
    for (int t = 0; t < LL; t++) {
        k_dect<<<8, blk, 0, stream>>>(t);
        k_attn<<<BB, blk, 0, stream>>>(t, att_v);
        k_dec_step<<<8, blk, 0, stream>>>(t, dec_b);
    }
    // logits GEMM (+bias, + (t,b)->(b,t) remap) straight into d_out
    k_gemm<<<dim3(VT / 128, RT / 128), blk, 0, stream>>>(3, 1024, 3, 1024, RT, VT, 1024, 1, h2o_b, out, -1);
    // in-place log-softmax
    k_lsm<<<RT, blk, 0, stream>>>(out);
}

// Round 3
// 7031.239 us; speedup vs baseline: 1.3131x; 1.3131x over previous
//
#include <hip/hip_runtime.h>
#include <hip/hip_bf16.h>
#include <math.h>

#define BB 64
#define LL 64
#define EE 512
#define HH 512
#define G4 2048
#define VT 32000
#define RT 4096  // LL*BB

typedef unsigned short u16;
typedef __attribute__((ext_vector_type(8))) unsigned short ushort8;
typedef __attribute__((ext_vector_type(8))) short bf16x8;
typedef __attribute__((ext_vector_type(4))) float f32x4;

// ---------------- static device scratch ----------------
__device__ u16   gW2T[(size_t)VT * 1024];   // h2o_W^T  (VT x 1024) bf16
__device__ u16   gEncWxT[G4 * EE];
__device__ u16   gEncWhT[G4 * HH];
__device__ u16   gAttWhT[HH * HH];
__device__ u16   gAttWsT[HH * HH];
__device__ u16   gDecWxTe[G4 * EE];         // dec_Wx rows 0..511 ^T
__device__ u16   gDecWxTc[G4 * HH];         // dec_Wx rows 512..1023 ^T
__device__ u16   gDecWhT[G4 * HH];
__device__ u16   gSrcEmb[RT * EE];
__device__ u16   gTgtEmb[RT * EE];
__device__ float gXWxE[(size_t)RT * G4];    // src_emb @ enc_Wx + enc_b
__device__ float gXWxD[(size_t)RT * G4];    // tgt_emb @ dec_Wx[:512] + dec_b
__device__ u16   gEncHb[(size_t)RT * HH];   // enc_hiddens bf16, row r=t*64+b
__device__ float gEncT[(size_t)RT * HH];    // enc_hiddens @ att_Wh (fp32)
__device__ u16   gHcat[(size_t)RT * 1024];  // [h | ctx] bf16 per dec step
__device__ float gDecT[BB * HH];            // h_prev @ att_Ws (per step)
__device__ float gZH[BB * G4];              // h_prev @ dec_Wh (per step)
__device__ float gC[BB * HH];               // LSTM cell state fp32
__device__ float gAv[HH];                   // att_v copy
__device__ unsigned gBar;                   // grid barrier counter

__device__ __forceinline__ u16 f2b(float f) {
    union { float f; unsigned u; } v{f};
    unsigned r = v.u + 0x7fffu + ((v.u >> 16) & 1u);
    return (u16)(r >> 16);
}
__device__ __forceinline__ float b2f(u16 x) {
    union { unsigned u; float f; } v; v.u = ((unsigned)x) << 16; return v.f;
}
__device__ __forceinline__ float sigm(float x) { return 1.f / (1.f + __expf(-x)); }
__device__ __forceinline__ float ftanh(float x) {
    x = fminf(15.f, fmaxf(-15.f, x));
    float e = __expf(2.f * x);
    return (e - 1.f) / (e + 1.f);
}

// grid barrier (requires cooperative launch co-residency; gBar==0 at kernel entry)
__device__ __forceinline__ void gsync(unsigned nb, unsigned& gen) {
    __syncthreads();
    if (threadIdx.x == 0) {
        __threadfence();
        __hip_atomic_fetch_add(&gBar, 1u, __ATOMIC_RELEASE, __HIP_MEMORY_SCOPE_AGENT);
        gen += nb;
        while (__hip_atomic_load(&gBar, __ATOMIC_ACQUIRE, __HIP_MEMORY_SCOPE_AGENT) < gen) {
            __builtin_amdgcn_s_sleep(2);
        }
        __threadfence();
    }
    __syncthreads();
}

__device__ __forceinline__ void g2l16(const u16* g, u16* l) {
    __builtin_amdgcn_global_load_lds(
        (const __attribute__((address_space(1))) unsigned int*)g,
        (__attribute__((address_space(3))) unsigned int*)l, 16, 0, 0);
}

// ---------------- transpose fp32 (R x C) -> bf16 (C x R) ----------------
__device__ inline u16* bf16sel(int s) {
    switch (s) {
        case 0: return gW2T;    case 1: return gEncWxT; case 2: return gEncWhT;
        case 3: return gAttWhT; case 4: return gAttWsT; case 5: return gDecWxTe;
        case 6: return gDecWxTc; default: return gDecWhT;
    }
}

__global__ __launch_bounds__(256) void k_transpose(const float* __restrict__ in, int R, int C, int sel) {
    __shared__ float tile[32][33];
    int tx = threadIdx.x & 31, ty0 = threadIdx.x >> 5;
    int c0 = blockIdx.x * 32, r0 = blockIdx.y * 32;
#pragma unroll
    for (int k = 0; k < 4; k++) {
        int ty = ty0 + k * 8;
        tile[ty][tx] = in[(size_t)(r0 + ty) * C + c0 + tx];
    }
    __syncthreads();
    u16* out = bf16sel(sel);
#pragma unroll
    for (int k = 0; k < 4; k++) {
        int ty = ty0 + k * 8;
        out[(size_t)(c0 + ty) * R + r0 + tx] = f2b(tile[tx][ty]);
    }
}

// ---------------- embedding gather -> bf16, row r = t*64+b ----------------
__global__ __launch_bounds__(256) void k_gather(const int* __restrict__ tok, const float* __restrict__ tab, int sel) {
    int r = blockIdx.x;
    int b = r & 63, t = r >> 6;
    int token = tok[b * LL + t];
    u16* dst = (sel == 0) ? gSrcEmb : gTgtEmb;
    const float* srow = tab + (size_t)token * EE;
    for (int e = threadIdx.x; e < EE; e += 256)
        dst[(size_t)r * EE + e] = f2b(srow[e]);
}

__global__ __launch_bounds__(256) void k_zero() {
    int i = blockIdx.x * 256 + threadIdx.x;  // 128 blocks
    gC[i] = 0.f;
    if (i == 0) gBar = 0u;
}

__global__ __launch_bounds__(256) void k_rst(const float* __restrict__ av) {
    int t = threadIdx.x;
    gAv[t] = av[t];
    gAv[t + 256] = av[t + 256];
    if (t == 0) gBar = 0u;
}

// ---------------- generic bf16 MFMA GEMM: C(MxN) = A(MxK) * B^T(NxK) ----------------
// epi 0: C = v ; epi 2: C = v + bias[col]
__global__ __launch_bounds__(256) void k_gemm(int selA, int lda, int selB, int ldb,
                                              int M, int N, int K, int epi,
                                              const float* __restrict__ bias, int selOut) {
    __shared__ u16 sA[128 * 72];
    __shared__ u16 sB[128 * 72];
    const u16* Ag;
    switch (selA) { case 0: Ag = gSrcEmb; break; case 1: Ag = gTgtEmb; break; default: Ag = gEncHb; }
    const u16* Bg;
    switch (selB) { case 0: Bg = gEncWxT; break; case 1: Bg = gDecWxTe; break; default: Bg = gAttWhT; }
    float* Cg;
    if (selOut == 0) Cg = gXWxE; else if (selOut == 1) Cg = gXWxD; else Cg = gEncT;

    int tid = threadIdx.x, l = tid & 63, wid = tid >> 6, wr = wid >> 1, wc = wid & 1;
    int ar = l & 15, ak = (l >> 4) * 8;
    int rowM = blockIdx.y * 128, colN = blockIdx.x * 128;
    f32x4 acc[4][4];
#pragma unroll
    for (int m = 0; m < 4; m++)
#pragma unroll
        for (int n = 0; n < 4; n++) acc[m][n] = (f32x4){0.f, 0.f, 0.f, 0.f};

    for (int k0 = 0; k0 < K; k0 += 64) {
#pragma unroll
        for (int it = 0; it < 4; it++) {
            int idx = it * 256 + tid;
            int row = idx >> 3, cc = idx & 7;
            *(ushort8*)(sA + row * 72 + cc * 8) =
                *(const ushort8*)(Ag + (size_t)(rowM + row) * lda + k0 + cc * 8);
            *(ushort8*)(sB + row * 72 + cc * 8) =
                *(const ushort8*)(Bg + (size_t)(colN + row) * ldb + k0 + cc * 8);
        }
        __syncthreads();
#pragma unroll
        for (int ks = 0; ks < 2; ks++) {
            bf16x8 a[4], b[4];
#pragma unroll
            for (int m = 0; m < 4; m++) a[m] = *(const bf16x8*)(sA + (wr * 64 + m * 16 + ar) * 72 + ks * 32 + ak);
#pragma unroll
            for (int n = 0; n < 4; n++) b[n] = *(const bf16x8*)(sB + (wc * 64 + n * 16 + ar) * 72 + ks * 32 + ak);
#pragma unroll
            for (int m = 0; m < 4; m++)
#pragma unroll
                for (int n = 0; n < 4; n++)
                    acc[m][n] = __builtin_amdgcn_mfma_f32_16x16x32_bf16(a[m], b[n], acc[m][n], 0, 0, 0);
        }
        __syncthreads();
    }
    int rb = (l >> 4) * 4;
#pragma unroll
    for (int m = 0; m < 4; m++)
#pragma unroll
        for (int n = 0; n < 4; n++)
#pragma unroll
            for (int ri = 0; ri < 4; ri++) {
                int row = rowM + wr * 64 + m * 16 + rb + ri;
                int col = colN + wc * 64 + n * 16 + ar;
                float v = acc[m][n][ri];
                if (epi == 0) Cg[(size_t)row * N + col] = v;
                else Cg[(size_t)row * N + col] = v + bias[col];
            }
}

// ---------------- logits GEMM (m97 structure): out[(b*64+t)*VT+col] = A@B^T + bias ----------------
__global__ __launch_bounds__(256) void k_gemm_big(const float* __restrict__ bias, float* __restrict__ out) {
    __shared__ u16 sA[128 * 64];
    __shared__ u16 sB[128 * 64];
    int tid = threadIdx.x, l = tid & 63, wid = tid >> 6, wr = wid >> 1, wc = wid & 1;
    int ar = l & 15, ak = (l >> 4) * 8, rb = (l >> 4) * 4;
    int bid = blockIdx.x;
    int bxx = bid % (VT / 128), byy = bid / (VT / 128);
    int rowM = byy * 128, colN = bxx * 128;
    f32x4 acc[4][4];
#pragma unroll
    for (int m = 0; m < 4; m++)
#pragma unroll
        for (int n = 0; n < 4; n++) acc[m][n] = (f32x4){0.f, 0.f, 0.f, 0.f};

    int srow = wid * 32 + (l >> 3);
    int scol = (l & 7) * 8;
    for (int k0 = 0; k0 < 1024; k0 += 64) {
#pragma unroll
        for (int c = 0; c < 4; c++) {
            int r = srow + c * 8;
            g2l16(gHcat + (size_t)(rowM + r) * 1024 + k0 + scol, sA + r * 64 + scol);
            g2l16(gW2T + (size_t)(colN + r) * 1024 + k0 + scol, sB + r * 64 + scol);
        }
        __syncthreads();
#pragma unroll
        for (int ks = 0; ks < 2; ks++) {
            bf16x8 a[4], b[4];
#pragma unroll
            for (int m = 0; m < 4; m++) a[m] = *(const bf16x8*)(sA + (wr * 64 + m * 16 + ar) * 64 + ks * 32 + ak);
#pragma unroll
            for (int n = 0; n < 4; n++) b[n] = *(const bf16x8*)(sB + (wc * 64 + n * 16 + ar) * 64 + ks * 32 + ak);
#pragma unroll
            for (int m = 0; m < 4; m++)
#pragma unroll
                for (int n = 0; n < 4; n++)
                    acc[m][n] = __builtin_amdgcn_mfma_f32_16x16x32_bf16(a[m], b[n], acc[m][n], 0, 0, 0);
        }
        __syncthreads();
    }
#pragma unroll
    for (int m = 0; m < 4; m++)
#pragma unroll
        for (int n = 0; n < 4; n++)
#pragma unroll
            for (int ri = 0; ri < 4; ri++) {
                int row = rowM + wr * 64 + m * 16 + rb + ri;
                int col = colN + wc * 64 + n * 16 + ar;
                out[(size_t)((row & 63) * 64 + (row >> 6)) * VT + col] = acc[m][n][ri] + bias[col];
            }
}

// ---------------- encoder: 1 cooperative kernel, 16 blocks, Wh in LDS ----------------
__global__ __launch_bounds__(256) void k_encoder(int dummy) {
    __shared__ u16 sW[64 * 1024];  // 128 rows (g*32+j) x 512 K, XOR-swizzled
    int tid = threadIdx.x, l = tid & 63, wid = tid >> 6;
    int bx = blockIdx.x;  // hcols [bx*32, bx*32+32)
    for (int it = 0; it < 32; it++) {
        int ch = it * 256 + tid;
        int r = ch >> 6, kc = ch & 63;
        int gc = (r >> 5) * 512 + bx * 32 + (r & 31);
        ushort8 v = *(const ushort8*)(gEncWhT + (size_t)gc * 512 + kc * 8);
        *(ushort8*)((char*)sW + ((r * 1024 + kc * 16) ^ ((r & 7) << 4))) = v;
    }
    __syncthreads();
    int ar = l & 15, ak = (l >> 4) * 8, rb = (l >> 4) * 4;
    int rowhalf = wid & 1, hg = wid >> 1;
    int hbase = bx * 32 + hg * 16;
    unsigned gen = 0;
    for (int t = 0; t < LL; t++) {
        f32x4 acc[2][4];
#pragma unroll
        for (int m = 0; m < 2; m++)
#pragma unroll
            for (int g = 0; g < 4; g++) acc[m][g] = (f32x4){0.f, 0.f, 0.f, 0.f};
        if (t > 0) {
            const u16* hp = gEncHb + (size_t)(t - 1) * (BB * HH);
#pragma unroll
            for (int kk = 0; kk < 16; kk++) {
                int k = kk * 32 + ak;
                bf16x8 a[2], b[4];
                a[0] = *(const bf16x8*)(hp + (size_t)(rowhalf * 32 + ar) * HH + k);
                a[1] = *(const bf16x8*)(hp + (size_t)(rowhalf * 32 + 16 + ar) * HH + k);
#pragma unroll
                for (int g = 0; g < 4; g++) {
                    int r = g * 32 + hg * 16 + ar;
                    b[g] = *(const bf16x8*)((char*)sW + ((r * 1024 + k * 2) ^ ((r & 7) << 4)));
                }
#pragma unroll
                for (int m = 0; m < 2; m++)
#pragma unroll
                    for (int g = 0; g < 4; g++)
                        acc[m][g] = __builtin_amdgcn_mfma_f32_16x16x32_bf16(a[m], b[g], acc[m][g], 0, 0, 0);
            }
        }
#pragma unroll
        for (int m = 0; m < 2; m++)
#pragma unroll
            for (int ri = 0; ri < 4; ri++) {
                int row = rowhalf * 32 + m * 16 + rb + ri;
                int rr = t * BB + row;
                int hcol = hbase + ar;
                const float* xw = gXWxE + (size_t)rr * G4;
                float zi = acc[m][0][ri] + xw[hcol];
                float zf = acc[m][1][ri] + xw[512 + hcol];
                float zg = acc[m][2][ri] + xw[1024 + hcol];
                float zo = acc[m][3][ri] + xw[1536 + hcol];
                float co = gC[row * HH + hcol];
                float cn = sigm(zf) * co + sigm(zi) * ftanh(zg);
                float hn = sigm(zo) * ftanh(cn);
                gC[row * HH + hcol] = cn;
                gEncHb[(size_t)rr * HH + hcol] = f2b(hn);
            }
        gsync(16, gen);
    }
}

// ---------------- decoder: 1 cooperative kernel, 64 blocks ----------------
// blocks 0..15: phase3 weights (WxTc, 128 rows); blocks 16..55: phase1 (Wh|Ws, 64 rows)
__global__ __launch_bounds__(256) void k_decoder(int dummy) {
    __shared__ u16 sW[64 * 1024];
    __shared__ float s_av[512];
    __shared__ float s_dt[512];
    __shared__ float s_att[64];
    __shared__ float s_red[256];
    int tid = threadIdx.x, l = tid & 63, wid = tid >> 6;
    int bx = blockIdx.x;
    if (bx < 16) {
        for (int it = 0; it < 32; it++) {
            int ch = it * 256 + tid;
            int r = ch >> 6, kc = ch & 63;
            int gc = (r >> 5) * 512 + bx * 32 + (r & 31);
            ushort8 v = *(const ushort8*)(gDecWxTc + (size_t)gc * 512 + kc * 8);
            *(ushort8*)((char*)sW + ((r * 1024 + kc * 16) ^ ((r & 7) << 4))) = v;
        }
    } else if (bx < 56) {
        for (int it = 0; it < 16; it++) {
            int ch = it * 256 + tid;
            int r = ch >> 6, kc = ch & 63;
            int c = (bx - 16) * 64 + r;
            const u16* srcp = (c < 2048) ? (gDecWhT + (size_t)c * 512) : (gAttWsT + (size_t)(c - 2048) * 512);
            ushort8 v = *(const ushort8*)(srcp + kc * 8);
            *(ushort8*)((char*)sW + ((r * 1024 + kc * 16) ^ ((r & 7) << 4))) = v;
        }
    }
    s_av[tid] = gAv[tid];
    s_av[tid + 256] = gAv[tid + 256];
    __syncthreads();
    int ar = l & 15, ak = (l >> 4) * 8, rb = (l >> 4) * 4;
    unsigned gen = 0;
    for (int t = 0; t < LL; t++) {
        // ---- phase 1: zH = h_prev @ dec_Wh (cols<2048) ; decT = h_prev @ att_Ws (cols>=2048)
        if (bx >= 16 && bx < 56) {
            const u16* hp; int hlda;
            if (t == 0) { hp = gEncHb + (size_t)63 * BB * HH; hlda = HH; }
            else        { hp = gHcat + (size_t)(t - 1) * BB * 1024; hlda = 1024; }
            f32x4 acc[4];
#pragma unroll
            for (int m = 0; m < 4; m++) acc[m] = (f32x4){0.f, 0.f, 0.f, 0.f};
#pragma unroll
            for (int kk = 0; kk < 16; kk++) {
                int k = kk * 32 + ak;
                int r = wid * 16 + ar;
                bf16x8 bfr = *(const bf16x8*)((char*)sW + ((r * 1024 + k * 2) ^ ((r & 7) << 4)));
#pragma unroll
                for (int m = 0; m < 4; m++) {
                    bf16x8 afr = *(const bf16x8*)(hp + (size_t)(m * 16 + ar) * hlda + k);
                    acc[m] = __builtin_amdgcn_mfma_f32_16x16x32_bf16(afr, bfr, acc[m], 0, 0, 0);
                }
            }
            int c = (bx - 16) * 64 + wid * 16 + ar;
#pragma unroll
            for (int m = 0; m < 4; m++)
#pragma unroll
                for (int ri = 0; ri < 4; ri++) {
                    int row = m * 16 + rb + ri;
                    float v = acc[m][ri];
                    if (c < 2048) gZH[row * G4 + c] = v;
                    else gDecT[row * HH + (c - 2048)] = v;
                }
        }
        gsync(64, gen);
        // ---- phase 2: attention for b = bx
        {
            int b = bx;
            s_dt[tid] = gDecT[b * HH + tid];
            s_dt[tid + 256] = gDecT[b * HH + tid + 256];
            __syncthreads();
            int s = tid >> 2, q = tid & 3;
            const float* et = gEncT + (size_t)(s * BB + b) * HH;
            float p = 0.f;
#pragma unroll 4
            for (int i = 0; i < 128; i++) {
                int h = i * 4 + q;
                p += ftanh(et[h] + s_dt[h]) * s_av[h];
            }
            s_red[tid] = p;
            __syncthreads();
            if (tid < 64) {
                float v = s_red[tid * 4] + s_red[tid * 4 + 1] + s_red[tid * 4 + 2] + s_red[tid * 4 + 3];
                float m = v;
                for (int o = 32; o; o >>= 1) m = fmaxf(m, __shfl_xor(m, o));
                float e = __expf(v - m);
                float ss = e;
                for (int o = 32; o; o >>= 1) ss += __shfl_xor(ss, o);
                s_att[tid] = e / ss;
            }
            __syncthreads();
            for (int h = tid; h < HH; h += 256) {
                float cc = 0.f;
                for (int s2 = 0; s2 < 64; s2++)
                    cc += s_att[s2] * b2f(gEncHb[(size_t)(s2 * BB + b) * HH + h]);
                gHcat[(size_t)(t * BB + b) * 1024 + 512 + h] = f2b(cc);
            }
        }
        gsync(64, gen);
        // ---- phase 3: z = ctx@WxTc + zH + xw(+bias) -> gates -> h
        if (bx < 16) {
            const u16* cx = gHcat + (size_t)t * BB * 1024 + 512;
            int rowhalf = wid & 1, hg = wid >> 1;
            f32x4 acc[2][4];
#pragma unroll
            for (int m = 0; m < 2; m++)
#pragma unroll
                for (int g = 0; g < 4; g++) acc[m][g] = (f32x4){0.f, 0.f, 0.f, 0.f};
#pragma unroll
            for (int kk = 0; kk < 16; kk++) {
                int k = kk * 32 + ak;
                bf16x8 a[2], b[4];
                a[0] = *(const bf16x8*)(cx + (size_t)(rowhalf * 32 + ar) * 1024 + k);
                a[1] = *(const bf16x8*)(cx + (size_t)(rowhalf * 32 + 16 + ar) * 1024 + k);
#pragma unroll
                for (int g = 0; g < 4; g++) {
                    int r = g * 32 + hg * 16 + ar;
                    b[g] = *(const bf16x8*)((char*)sW + ((r * 1024 + k * 2) ^ ((r & 7) << 4)));
                }
#pragma unroll
                for (int m = 0; m < 2; m++)
#pragma unroll
                    for (int g = 0; g < 4; g++)
                        acc[m][g] = __builtin_amdgcn_mfma_f32_16x16x32_bf16(a[m], b[g], acc[m][g], 0, 0, 0);
            }
            int hbase = bx * 32 + hg * 16;
#pragma unroll
            for (int m = 0; m < 2; m++)
#pragma unroll
                for (int ri = 0; ri < 4; ri++) {
                    int row = rowhalf * 32 + m * 16 + rb + ri;
                    int rr = t * BB + row;
                    int hcol = hbase + ar;
                    const float* xw = gXWxD + (size_t)rr * G4;
                    const float* zh = gZH + row * G4;
                    float zi = acc[m][0][ri] + xw[hcol] + zh[hcol];
                    float zf = acc[m][1][ri] + xw[512 + hcol] + zh[512 + hcol];
                    float zg = acc[m][2][ri] + xw[1024 + hcol] + zh[1024 + hcol];
                    float zo = acc[m][3][ri] + xw[1536 + hcol] + zh[1536 + hcol];
                    float co = gC[row * HH + hcol];
                    float cn = sigm(zf) * co + sigm(zi) * ftanh(zg);
                    float hn = sigm(zo) * ftanh(cn);
                    gC[row * HH + hcol] = cn;
                    gHcat[(size_t)rr * 1024 + hcol] = f2b(hn);
                }
        }
        gsync(64, gen);
    }
}

// ---------------- log-softmax in place, online max/sum, float4 ----------------
__global__ __launch_bounds__(256) void k_lsm(float* __restrict__ out) {
    int row = blockIdx.x, tid = threadIdx.x;
    float4* p4 = (float4*)(out + (size_t)row * VT);
    float m = -1e30f, s = 0.f;
    for (int i = tid; i < VT / 4; i += 256) {
        float4 v = p4[i];
        float mx = fmaxf(fmaxf(v.x, v.y), fmaxf(v.z, v.w));
        float mn = fmaxf(m, mx);
        s = s * __expf(m - mn) + __expf(v.x - mn) + __expf(v.y - mn) + __expf(v.z - mn) + __expf(v.w - mn);
        m = mn;
    }
    for (int o = 32; o; o >>= 1) {
        float m2 = __shfl_xor(m, o), s2 = __shfl_xor(s, o);
        float mn = fmaxf(m, m2);
        s = s * __expf(m - mn) + s2 * __expf(m2 - mn);
        m = mn;
    }
    __shared__ float rm[4], rs[4];
    if ((tid & 63) == 0) { rm[tid >> 6] = m; rs[tid >> 6] = s; }
    __syncthreads();
    float mm = fmaxf(fmaxf(rm[0], rm[1]), fmaxf(rm[2], rm[3]));
    float ss = rs[0] * __expf(rm[0] - mm) + rs[1] * __expf(rm[1] - mm) +
               rs[2] * __expf(rm[2] - mm) + rs[3] * __expf(rm[3] - mm);
    float lse = mm + __logf(ss);
    for (int i = tid; i < VT / 4; i += 256) {
        float4 v = p4[i];
        v.x -= lse; v.y -= lse; v.z -= lse; v.w -= lse;
        p4[i] = v;
    }
}

extern "C" void kernel_launch(void* const* d_in, const int* in_sizes, int n_in,
                              void* d_out, int out_size, void* d_ws, size_t ws_size,
                              hipStream_t stream) {
    const int*   src       = (const int*)d_in[0];
    const int*   tgt       = (const int*)d_in[1];
    const float* src_embed = (const float*)d_in[2];
    const float* enc_Wx    = (const float*)d_in[3];
    const float* enc_Wh    = (const float*)d_in[4];
    const float* enc_b     = (const float*)d_in[5];
    const float* tgt_embed = (const float*)d_in[6];
    const float* att_Wh    = (const float*)d_in[7];
    const float* att_Ws    = (const float*)d_in[8];
    const float* att_v     = (const float*)d_in[9];
    const float* dec_Wx    = (const float*)d_in[10];
    const float* dec_Wh    = (const float*)d_in[11];
    const float* dec_b     = (const float*)d_in[12];
    const float* h2o_W     = (const float*)d_in[13];
    const float* h2o_b     = (const float*)d_in[14];
    float* out = (float*)d_out;
    dim3 blk(256);

    k_transpose<<<dim3(VT / 32, 1024 / 32), blk, 0, stream>>>(h2o_W, 1024, VT, 0);
    k_transpose<<<dim3(G4 / 32, EE / 32), blk, 0, stream>>>(enc_Wx, EE, G4, 1);
    k_transpose<<<dim3(G4 / 32, HH / 32), blk, 0, stream>>>(enc_Wh, HH, G4, 2);
    k_transpose<<<dim3(HH / 32, HH / 32), blk, 0, stream>>>(att_Wh, HH, HH, 3);
    k_transpose<<<dim3(HH / 32, HH / 32), blk, 0, stream>>>(att_Ws, HH, HH, 4);
    k_transpose<<<dim3(G4 / 32, EE / 32), blk, 0, stream>>>(dec_Wx, EE, G4, 5);
    k_transpose<<<dim3(G4 / 32, HH / 32), blk, 0, stream>>>(dec_Wx + (size_t)512 * G4, HH, G4, 6);
    k_transpose<<<dim3(G4 / 32, HH / 32), blk, 0, stream>>>(dec_Wh, HH, G4, 7);
    k_gather<<<RT, blk, 0, stream>>>(src, src_embed, 0);
    k_gather<<<RT, blk, 0, stream>>>(tgt, tgt_embed, 1);
    k_zero<<<128, blk, 0, stream>>>();
    // hoisted input GEMMs (+bias folded)
    k_gemm<<<dim3(G4 / 128, RT / 128), blk, 0, stream>>>(0, 512, 0, 512, RT, G4, 512, 2, enc_b, 0);
    k_gemm<<<dim3(G4 / 128, RT / 128), blk, 0, stream>>>(1, 512, 1, 512, RT, G4, 512, 2, dec_b, 1);
    // encoder (cooperative)
    int dummy = 0;
    void* eargs[] = { &dummy };
    hipLaunchCooperativeKernel((const void*)k_encoder, dim3(16), dim3(256), eargs, 0, stream);
    // enc_t = enc_hiddens @ att_Wh
    k_gemm<<<dim3(HH / 128, RT / 128), blk, 0, stream>>>(2, 512, 2, 512, RT, HH, 512, 0, nullptr, 2);
    // reset barrier + stage att_v
    k_rst<<<1, blk, 0, stream>>>(att_v);
    // decoder (cooperative)
    hipLaunchCooperativeKernel((const void*)k_decoder, dim3(64), dim3(256), eargs, 0, stream);
    // logits GEMM straight into d_out (+bias, (t,b)->(b,t) remap)
    k_gemm_big<<<(VT / 128) * (RT / 128), blk, 0, stream>>>(h2o_b, out);
    // in-place log-softmax
    k_lsm<<<RT, blk, 0, stream>>>(out);
}

// Round 4
// 4182.471 us; speedup vs baseline: 2.2075x; 1.6811x over previous
//
#include <hip/hip_runtime.h>
#include <hip/hip_bf16.h>
#include <math.h>

#define BB 64
#define LL 64
#define EE 512
#define HH 512
#define G4 2048
#define VT 32000
#define RT 4096  // LL*BB

typedef unsigned short u16;
typedef unsigned int u32;
typedef __attribute__((ext_vector_type(8))) unsigned short ushort8;
typedef __attribute__((ext_vector_type(8))) short bf16x8;
typedef __attribute__((ext_vector_type(4))) float f32x4;

// ---------------- static device scratch ----------------
__device__ u16   gW2T[(size_t)VT * 1024];   // h2o_W^T (VT x 1024) bf16
__device__ u16   gEncWxT[G4 * EE];
__device__ u16   gEncWhT[G4 * HH];
__device__ u16   gAttWhT[HH * HH];
__device__ u16   gDecWxTe[G4 * EE];
__device__ u16   gDecWxTc[G4 * HH];
__device__ u16   gDecWhT[G4 * HH];
__device__ u16   gWsB[HH * HH];             // att_Ws bf16, ORIGINAL [k][c] layout
__device__ u16   gSrcEmb[RT * EE];
__device__ u16   gTgtEmb[RT * EE];
__device__ float gXWxE[(size_t)RT * G4];    // src_emb @ enc_Wx + enc_b
__device__ float gXWxD[(size_t)RT * G4];    // tgt_emb @ dec_Wx[:512] + dec_b
__device__ u16   gEncHb[(size_t)RT * HH];   // enc h bf16, [t*64+b][h]
__device__ u16   gEncHb2[(size_t)RT * HH];  // enc h bf16, [b*64+t][h]
__device__ float gEncT[(size_t)RT * HH];    // enc_hiddens @ att_Wh, [b*64+s][h]
__device__ u16   gHcat[(size_t)RT * 1024];  // [h | ctx] bf16, row rr=t*64+b
__device__ float gC[BB * HH];               // LSTM cell state
__device__ float gAv[HH];
__device__ unsigned gBar;

__device__ __forceinline__ u16 f2b(float f) {
    union { float f; unsigned u; } v{f};
    unsigned r = v.u + 0x7fffu + ((v.u >> 16) & 1u);
    return (u16)(r >> 16);
}
__device__ __forceinline__ float b2f(u16 x) {
    union { unsigned u; float f; } v; v.u = ((unsigned)x) << 16; return v.f;
}
__device__ __forceinline__ float sigm(float x) { return 1.f / (1.f + __expf(-x)); }
__device__ __forceinline__ float ftanh(float x) {
    x = fminf(15.f, fmaxf(-15.f, x));
    float e = __expf(2.f * x);
    return (e - 1.f) / (e + 1.f);
}

// grid barrier: RELEASE arrive, RELAXED spin (no per-poll cache ops), ACQUIRE once on exit
__device__ __forceinline__ void gsync(unsigned nb, unsigned& gen) {
    __syncthreads();
    if (threadIdx.x == 0) {
        gen += nb;
        __hip_atomic_fetch_add(&gBar, 1u, __ATOMIC_RELEASE, __HIP_MEMORY_SCOPE_AGENT);
        while (__hip_atomic_load(&gBar, __ATOMIC_RELAXED, __HIP_MEMORY_SCOPE_AGENT) < gen)
            __builtin_amdgcn_s_sleep(1);
        (void)__hip_atomic_load(&gBar, __ATOMIC_ACQUIRE, __HIP_MEMORY_SCOPE_AGENT);
    }
    __syncthreads();
}

__device__ __forceinline__ void g2l16(const u16* g, u16* l) {
    __builtin_amdgcn_global_load_lds(
        (const __attribute__((address_space(1))) unsigned int*)g,
        (__attribute__((address_space(3))) unsigned int*)l, 16, 0, 0);
}

// ---------------- transpose fp32 (R x C) -> bf16 (C x R) ----------------
__device__ inline u16* bf16sel(int s) {
    switch (s) {
        case 0: return gW2T;    case 1: return gEncWxT; case 2: return gEncWhT;
        case 3: return gAttWhT; case 4: return gDecWxTe; case 5: return gDecWxTc;
        default: return gDecWhT;
    }
}

__global__ __launch_bounds__(256) void k_transpose(const float* __restrict__ in, int R, int C, int sel) {
    __shared__ float tile[32][33];
    int tx = threadIdx.x & 31, ty0 = threadIdx.x >> 5;
    int c0 = blockIdx.x * 32, r0 = blockIdx.y * 32;
#pragma unroll
    for (int k = 0; k < 4; k++) {
        int ty = ty0 + k * 8;
        tile[ty][tx] = in[(size_t)(r0 + ty) * C + c0 + tx];
    }
    __syncthreads();
    u16* out = bf16sel(sel);
#pragma unroll
    for (int k = 0; k < 4; k++) {
        int ty = ty0 + k * 8;
        out[(size_t)(c0 + ty) * R + r0 + tx] = f2b(tile[tx][ty]);
    }
}

// fp32 -> bf16 elementwise (att_Ws, keep [k][c] layout)
__global__ __launch_bounds__(256) void k_tobf(const float* __restrict__ in) {
    int i = blockIdx.x * 256 + threadIdx.x;
    gWsB[i] = f2b(in[i]);
}

__global__ __launch_bounds__(256) void k_gather(const int* __restrict__ tok, const float* __restrict__ tab, int sel) {
    int r = blockIdx.x;
    int b = r & 63, t = r >> 6;
    int token = tok[b * LL + t];
    u16* dst = (sel == 0) ? gSrcEmb : gTgtEmb;
    const float* srow = tab + (size_t)token * EE;
    for (int e = threadIdx.x; e < EE; e += 256)
        dst[(size_t)r * EE + e] = f2b(srow[e]);
}

__global__ __launch_bounds__(256) void k_zero() {
    int i = blockIdx.x * 256 + threadIdx.x;  // 128 blocks
    gC[i] = 0.f;
    if (i == 0) gBar = 0u;
}

__global__ __launch_bounds__(256) void k_rst(const float* __restrict__ av) {
    int t = threadIdx.x;
    gAv[t] = av[t];
    gAv[t + 256] = av[t + 256];
    if (t == 0) gBar = 0u;
}

// ---------------- generic bf16 MFMA GEMM: C(MxN) = A(MxK) * B^T(NxK) ----------------
// epi 2: C[row*N+col]=v+bias[col]; epi 3: C[((row&63)*64+(row>>6))*N+col]=v (b-major remap)
__global__ __launch_bounds__(256) void k_gemm(int selA, int lda, int selB, int ldb,
                                              int M, int N, int K, int epi,
                                              const float* __restrict__ bias, int selOut) {
    __shared__ u16 sA[128 * 72];
    __shared__ u16 sB[128 * 72];
    const u16* Ag;
    switch (selA) { case 0: Ag = gSrcEmb; break; case 1: Ag = gTgtEmb; break; default: Ag = gEncHb; }
    const u16* Bg;
    switch (selB) { case 0: Bg = gEncWxT; break; case 1: Bg = gDecWxTe; break; default: Bg = gAttWhT; }
    float* Cg;
    if (selOut == 0) Cg = gXWxE; else if (selOut == 1) Cg = gXWxD; else Cg = gEncT;

    int tid = threadIdx.x, l = tid & 63, wid = tid >> 6, wr = wid >> 1, wc = wid & 1;
    int ar = l & 15, ak = (l >> 4) * 8;
    int rowM = blockIdx.y * 128, colN = blockIdx.x * 128;
    f32x4 acc[4][4];
#pragma unroll
    for (int m = 0; m < 4; m++)
#pragma unroll
        for (int n = 0; n < 4; n++) acc[m][n] = (f32x4){0.f, 0.f, 0.f, 0.f};

    for (int k0 = 0; k0 < K; k0 += 64) {
#pragma unroll
        for (int it = 0; it < 4; it++) {
            int idx = it * 256 + tid;
            int row = idx >> 3, cc = idx & 7;
            *(ushort8*)(sA + row * 72 + cc * 8) =
                *(const ushort8*)(Ag + (size_t)(rowM + row) * lda + k0 + cc * 8);
            *(ushort8*)(sB + row * 72 + cc * 8) =
                *(const ushort8*)(Bg + (size_t)(colN + row) * ldb + k0 + cc * 8);
        }
        __syncthreads();
#pragma unroll
        for (int ks = 0; ks < 2; ks++) {
            bf16x8 a[4], b[4];
#pragma unroll
            for (int m = 0; m < 4; m++) a[m] = *(const bf16x8*)(sA + (wr * 64 + m * 16 + ar) * 72 + ks * 32 + ak);
#pragma unroll
            for (int n = 0; n < 4; n++) b[n] = *(const bf16x8*)(sB + (wc * 64 + n * 16 + ar) * 72 + ks * 32 + ak);
#pragma unroll
            for (int m = 0; m < 4; m++)
#pragma unroll
                for (int n = 0; n < 4; n++)
                    acc[m][n] = __builtin_amdgcn_mfma_f32_16x16x32_bf16(a[m], b[n], acc[m][n], 0, 0, 0);
        }
        __syncthreads();
    }
    int rb = (l >> 4) * 4;
#pragma unroll
    for (int m = 0; m < 4; m++)
#pragma unroll
        for (int n = 0; n < 4; n++)
#pragma unroll
            for (int ri = 0; ri < 4; ri++) {
                int row = rowM + wr * 64 + m * 16 + rb + ri;
                int col = colN + wc * 64 + n * 16 + ar;
                float v = acc[m][n][ri];
                if (epi == 2) Cg[(size_t)row * N + col] = v + bias[col];
                else Cg[(size_t)((row & 63) * 64 + (row >> 6)) * N + col] = v;
            }
}

// ---------------- logits GEMM (m97 structure + XCD swizzle) ----------------
__global__ __launch_bounds__(256) void k_gemm_big(const float* __restrict__ bias, float* __restrict__ out) {
    __shared__ u16 sA[128 * 64];
    __shared__ u16 sB[128 * 64];
    int tid = threadIdx.x, l = tid & 63, wid = tid >> 6, wr = wid >> 1, wc = wid & 1;
    int ar = l & 15, ak = (l >> 4) * 8, rb = (l >> 4) * 4;
    int bid = (blockIdx.x & 7) * 1000 + (blockIdx.x >> 3);  // 8000 blocks, XCD-chunked
    int bxx = bid % (VT / 128), byy = bid / (VT / 128);
    int rowM = byy * 128, colN = bxx * 128;
    f32x4 acc[4][4];
#pragma unroll
    for (int m = 0; m < 4; m++)
#pragma unroll
        for (int n = 0; n < 4; n++) acc[m][n] = (f32x4){0.f, 0.f, 0.f, 0.f};

    int srow = wid * 32 + (l >> 3);
    int scol = (l & 7) * 8;
    for (int k0 = 0; k0 < 1024; k0 += 64) {
#pragma unroll
        for (int c = 0; c < 4; c++) {
            int r = srow + c * 8;
            g2l16(gHcat + (size_t)(rowM + r) * 1024 + k0 + scol, sA + r * 64 + scol);
            g2l16(gW2T + (size_t)(colN + r) * 1024 + k0 + scol, sB + r * 64 + scol);
        }
        __syncthreads();
#pragma unroll
        for (int ks = 0; ks < 2; ks++) {
            bf16x8 a[4], b[4];
#pragma unroll
            for (int m = 0; m < 4; m++) a[m] = *(const bf16x8*)(sA + (wr * 64 + m * 16 + ar) * 64 + ks * 32 + ak);
#pragma unroll
            for (int n = 0; n < 4; n++) b[n] = *(const bf16x8*)(sB + (wc * 64 + n * 16 + ar) * 64 + ks * 32 + ak);
#pragma unroll
            for (int m = 0; m < 4; m++)
#pragma unroll
                for (int n = 0; n < 4; n++)
                    acc[m][n] = __builtin_amdgcn_mfma_f32_16x16x32_bf16(a[m], b[n], acc[m][n], 0, 0, 0);
        }
        __syncthreads();
    }
#pragma unroll
    for (int m = 0; m < 4; m++)
#pragma unroll
        for (int n = 0; n < 4; n++)
#pragma unroll
            for (int ri = 0; ri < 4; ri++) {
                int row = rowM + wr * 64 + m * 16 + rb + ri;
                int col = colN + wc * 64 + n * 16 + ar;
                out[(size_t)((row & 63) * 64 + (row >> 6)) * VT + col] = acc[m][n][ri] + bias[col];
            }
}

// ---------------- encoder: 32 blocks, 16 h-cols each, 1 barrier/step ----------------
__global__ __launch_bounds__(256) void k_encoder(int dummy) {
    __shared__ u16 sW[64 * 512];  // 64 rows (g*16+c) x 512 K, XOR-swizzled, 64KB
    int tid = threadIdx.x, l = tid & 63, wid = tid >> 6;
    int j = blockIdx.x;  // h-cols [16j, 16j+16)
#pragma unroll
    for (int it = 0; it < 16; it++) {
        int idx = it * 256 + tid;
        int lr = idx >> 6, kc = idx & 63;
        int gcol = (lr >> 4) * 512 + j * 16 + (lr & 15);
        int off = (lr * 1024 + kc * 16) ^ ((lr & 7) << 4);
        *(ushort8*)((char*)sW + off) = *(const ushort8*)(gEncWhT + (size_t)gcol * 512 + kc * 8);
    }
    __syncthreads();
    int ar = l & 15, ak = (l >> 4) * 8, rb = (l >> 4) * 4;
    unsigned gen = 0;
    for (int t = 0; t < LL; t++) {
        f32x4 acc[4];
#pragma unroll
        for (int g = 0; g < 4; g++) acc[g] = (f32x4){0.f, 0.f, 0.f, 0.f};
        if (t > 0) {
            const u16* hp = gEncHb + (size_t)(t - 1) * (BB * HH);
#pragma unroll
            for (int kk = 0; kk < 16; kk++) {
                int k = kk * 32 + ak;
                bf16x8 a = *(const bf16x8*)(hp + (size_t)(wid * 16 + ar) * HH + k);
#pragma unroll
                for (int g = 0; g < 4; g++) {
                    int lr = g * 16 + ar;
                    bf16x8 b = *(const bf16x8*)((char*)sW + ((lr * 1024 + k * 2) ^ ((lr & 7) << 4)));
                    acc[g] = __builtin_amdgcn_mfma_f32_16x16x32_bf16(a, b, acc[g], 0, 0, 0);
                }
            }
        }
        int hcol = j * 16 + ar;
#pragma unroll
        for (int ri = 0; ri < 4; ri++) {
            int row = wid * 16 + rb + ri;
            int rr = t * BB + row;
            const float* xw = gXWxE + (size_t)rr * G4;
            float zi = acc[0][ri] + xw[hcol];
            float zf = acc[1][ri] + xw[512 + hcol];
            float zg = acc[2][ri] + xw[1024 + hcol];
            float zo = acc[3][ri] + xw[1536 + hcol];
            float co = gC[row * HH + hcol];
            float cn = sigm(zf) * co + sigm(zi) * ftanh(zg);
            float hn = sigm(zo) * ftanh(cn);
            gC[row * HH + hcol] = cn;
            u16 hb = f2b(hn);
            gEncHb[(size_t)rr * HH + hcol] = hb;
            gEncHb2[(size_t)(row * LL + t) * HH + hcol] = hb;
        }
        gsync(32, gen);
    }
}

// ---------------- decoder: 96 blocks (64 attention + 32 GEMM), 2 barriers/step ----------------
__global__ __launch_bounds__(256) void k_decoder(int dummy) {
    __shared__ u16 sWh[64 * 512];   // dec_Wh slice, 64KB
    __shared__ u16 sWx[64 * 512];   // dec_Wx[512:] slice, 64KB
    __shared__ float s_h[512];
    __shared__ float s_dt[512];
    __shared__ float s_av[512];
    __shared__ float s_att[64];
    __shared__ float s_red[256];
    int tid = threadIdx.x, l = tid & 63, wid = tid >> 6;
    int bx = blockIdx.x;
    int ar = l & 15, ak = (l >> 4) * 8, rb = (l >> 4) * 4;
    if (bx >= 64) {
        int j = bx - 64;  // h-cols [16j, 16j+16)
#pragma unroll
        for (int it = 0; it < 16; it++) {
            int idx = it * 256 + tid;
            int lr = idx >> 6, kc = idx & 63;
            int gcol = (lr >> 4) * 512 + j * 16 + (lr & 15);
            int off = (lr * 1024 + kc * 16) ^ ((lr & 7) << 4);
            *(ushort8*)((char*)sWh + off) = *(const ushort8*)(gDecWhT + (size_t)gcol * 512 + kc * 8);
            *(ushort8*)((char*)sWx + off) = *(const ushort8*)(gDecWxTc + (size_t)gcol * 512 + kc * 8);
        }
    } else {
        s_av[tid] = gAv[tid];
        s_av[tid + 256] = gAv[tid + 256];
    }
    __syncthreads();
    unsigned gen = 0;
    for (int t = 0; t < LL; t++) {
        f32x4 acc[4];
#pragma unroll
        for (int g = 0; g < 4; g++) acc[g] = (f32x4){0.f, 0.f, 0.f, 0.f};
        if (bx < 64) {
            // ======== attention for batch row b ========
            int b = bx;
            const u16* hp = (t == 0) ? (gEncHb + (size_t)(63 * BB + b) * HH)
                                     : (gHcat + (size_t)((t - 1) * BB + b) * 1024);
            s_h[tid] = b2f(hp[tid]);
            s_h[tid + 256] = b2f(hp[tid + 256]);
            __syncthreads();
            // dec_t = h @ att_Ws  (stream Ws from L2, [k][c] layout)
            int c = tid * 2;
            float p0 = 0.f, p1 = 0.f;
#pragma unroll 8
            for (int k = 0; k < 512; k++) {
                float hk = s_h[k];
                u32 w = *(const u32*)(gWsB + (size_t)k * 512 + c);
                p0 += hk * b2f((u16)(w & 0xffff));
                p1 += hk * b2f((u16)(w >> 16));
            }
            s_dt[c] = p0; s_dt[c + 1] = p1;
            __syncthreads();
            // energy
            int s = tid >> 2, q = tid & 3;
            const float* et = gEncT + (size_t)(b * LL + s) * HH;
            float p = 0.f;
#pragma unroll 4
            for (int i = 0; i < 128; i++) {
                int h = i * 4 + q;
                p += ftanh(et[h] + s_dt[h]) * s_av[h];
            }
            s_red[tid] = p;
            __syncthreads();
            if (tid < 64) {
                float v = s_red[tid * 4] + s_red[tid * 4 + 1] + s_red[tid * 4 + 2] + s_red[tid * 4 + 3];
                float m = v;
                for (int o = 32; o; o >>= 1) m = fmaxf(m, __shfl_xor(m, o));
                float e = __expf(v - m);
                float ss = e;
                for (int o = 32; o; o >>= 1) ss += __shfl_xor(ss, o);
                s_att[tid] = e / ss;
            }
            __syncthreads();
            // context
            float c0 = 0.f, c1 = 0.f;
            const u16* eh = gEncHb2 + (size_t)b * LL * HH;
#pragma unroll 8
            for (int s2 = 0; s2 < 64; s2++) {
                float a = s_att[s2];
                u32 w = *(const u32*)(eh + (size_t)s2 * HH + c);
                c0 += a * b2f((u16)(w & 0xffff));
                c1 += a * b2f((u16)(w >> 16));
            }
            u32 cw = (u32)f2b(c0) | ((u32)f2b(c1) << 16);
            *(u32*)(gHcat + (size_t)(t * BB + b) * 1024 + 512 + c) = cw;
            __syncthreads();
        } else {
            // ======== GEMM phase A: acc = h_prev @ Wh_slice ========
            const u16* hp; size_t hlda;
            if (t == 0) { hp = gEncHb + (size_t)63 * BB * HH; hlda = HH; }
            else        { hp = gHcat + (size_t)(t - 1) * BB * 1024; hlda = 1024; }
#pragma unroll
            for (int kk = 0; kk < 16; kk++) {
                int k = kk * 32 + ak;
                bf16x8 a = *(const bf16x8*)(hp + (size_t)(wid * 16 + ar) * hlda + k);
#pragma unroll
                for (int g = 0; g < 4; g++) {
                    int lr = g * 16 + ar;
                    bf16x8 b = *(const bf16x8*)((char*)sWh + ((lr * 1024 + k * 2) ^ ((lr & 7) << 4)));
                    acc[g] = __builtin_amdgcn_mfma_f32_16x16x32_bf16(a, b, acc[g], 0, 0, 0);
                }
            }
        }
        gsync(96, gen);  // SYNC1: ctx visible
        if (bx >= 64) {
            int j = bx - 64;
            // ======== GEMM phase B: acc += ctx @ WxC_slice; gates; write h ========
            const u16* cx = gHcat + (size_t)t * BB * 1024 + 512;
#pragma unroll
            for (int kk = 0; kk < 16; kk++) {
                int k = kk * 32 + ak;
                bf16x8 a = *(const bf16x8*)(cx + (size_t)(wid * 16 + ar) * 1024 + k);
#pragma unroll
                for (int g = 0; g < 4; g++) {
                    int lr = g * 16 + ar;
                    bf16x8 b = *(const bf16x8*)((char*)sWx + ((lr * 1024 + k * 2) ^ ((lr & 7) << 4)));
                    acc[g] = __builtin_amdgcn_mfma_f32_16x16x32_bf16(a, b, acc[g], 0, 0, 0);
                }
            }
            int hcol = j * 16 + ar;
#pragma unroll
            for (int ri = 0; ri < 4; ri++) {
                int row = wid * 16 + rb + ri;
                int rr = t * BB + row;
                const float* xw = gXWxD + (size_t)rr * G4;
                float zi = acc[0][ri] + xw[hcol];
                float zf = acc[1][ri] + xw[512 + hcol];
                float zg = acc[2][ri] + xw[1024 + hcol];
                float zo = acc[3][ri] + xw[1536 + hcol];
                float co = gC[row * HH + hcol];
                float cn = sigm(zf) * co + sigm(zi) * ftanh(zg);
                float hn = sigm(zo) * ftanh(cn);
                gC[row * HH + hcol] = cn;
                gHcat[(size_t)rr * 1024 + hcol] = f2b(hn);
            }
        }
        gsync(96, gen);  // SYNC2: h_t visible
    }
}

// ---------------- log-softmax in place, online max/sum, float4 ----------------
__global__ __launch_bounds__(256) void k_lsm(float* __restrict__ out) {
    int row = blockIdx.x, tid = threadIdx.x;
    float4* p4 = (float4*)(out + (size_t)row * VT);
    float m = -1e30f, s = 0.f;
    for (int i = tid; i < VT / 4; i += 256) {
        float4 v = p4[i];
        float mx = fmaxf(fmaxf(v.x, v.y), fmaxf(v.z, v.w));
        float mn = fmaxf(m, mx);
        s = s * __expf(m - mn) + __expf(v.x - mn) + __expf(v.y - mn) + __expf(v.z - mn) + __expf(v.w - mn);
        m = mn;
    }
    for (int o = 32; o; o >>= 1) {
        float m2 = __shfl_xor(m, o), s2 = __shfl_xor(s, o);
        float mn = fmaxf(m, m2);
        s = s * __expf(m - mn) + s2 * __expf(m2 - mn);
        m = mn;
    }
    __shared__ float rm[4], rs[4];
    if ((tid & 63) == 0) { rm[tid >> 6] = m; rs[tid >> 6] = s; }
    __syncthreads();
    float mm = fmaxf(fmaxf(rm[0], rm[1]), fmaxf(rm[2], rm[3]));
    float ss = rs[0] * __expf(rm[0] - mm) + rs[1] * __expf(rm[1] - mm) +
               rs[2] * __expf(rm[2] - mm) + rs[3] * __expf(rm[3] - mm);
    float lse = mm + __logf(ss);
    for (int i = tid; i < VT / 4; i += 256) {
        float4 v = p4[i];
        v.x -= lse; v.y -= lse; v.z -= lse; v.w -= lse;
        p4[i] = v;
    }
}

extern "C" void kernel_launch(void* const* d_in, const int* in_sizes, int n_in,
                              void* d_out, int out_size, void* d_ws, size_t ws_size,
                              hipStream_t stream) {
    const int*   src       = (const int*)d_in[0];
    const int*   tgt       = (const int*)d_in[1];
    const float* src_embed = (const float*)d_in[2];
    const float* enc_Wx    = (const float*)d_in[3];
    const float* enc_Wh    = (const float*)d_in[4];
    const float* enc_b     = (const float*)d_in[5];
    const float* tgt_embed = (const float*)d_in[6];
    const float* att_Wh    = (const float*)d_in[7];
    const float* att_Ws    = (const float*)d_in[8];
    const float* att_v     = (const float*)d_in[9];
    const float* dec_Wx    = (const float*)d_in[10];
    const float* dec_Wh    = (const float*)d_in[11];
    const float* dec_b     = (const float*)d_in[12];
    const float* h2o_W     = (const float*)d_in[13];
    const float* h2o_b     = (const float*)d_in[14];
    float* out = (float*)d_out;
    dim3 blk(256);

    k_transpose<<<dim3(VT / 32, 1024 / 32), blk, 0, stream>>>(h2o_W, 1024, VT, 0);
    k_transpose<<<dim3(G4 / 32, EE / 32), blk, 0, stream>>>(enc_Wx, EE, G4, 1);
    k_transpose<<<dim3(G4 / 32, HH / 32), blk, 0, stream>>>(enc_Wh, HH, G4, 2);
    k_transpose<<<dim3(HH / 32, HH / 32), blk, 0, stream>>>(att_Wh, HH, HH, 3);
    k_transpose<<<dim3(G4 / 32, EE / 32), blk, 0, stream>>>(dec_Wx, EE, G4, 4);
    k_transpose<<<dim3(G4 / 32, HH / 32), blk, 0, stream>>>(dec_Wx + (size_t)512 * G4, HH, G4, 5);
    k_transpose<<<dim3(G4 / 32, HH / 32), blk, 0, stream>>>(dec_Wh, HH, G4, 6);
    k_tobf<<<HH * HH / 256, blk, 0, stream>>>(att_Ws);
    k_gather<<<RT, blk, 0, stream>>>(src, src_embed, 0);
    k_gather<<<RT, blk, 0, stream>>>(tgt, tgt_embed, 1);
    k_zero<<<128, blk, 0, stream>>>();
    // hoisted input GEMMs (+bias folded)
    k_gemm<<<dim3(G4 / 128, RT / 128), blk, 0, stream>>>(0, 512, 0, 512, RT, G4, 512, 2, enc_b, 0);
    k_gemm<<<dim3(G4 / 128, RT / 128), blk, 0, stream>>>(1, 512, 1, 512, RT, G4, 512, 2, dec_b, 1);
    // encoder (cooperative, 32 blocks)
    int dummy = 0;
    void* eargs[] = { &dummy };
    hipLaunchCooperativeKernel((const void*)k_encoder, dim3(32), dim3(256), eargs, 0, stream);
    // enc_t = enc_hiddens @ att_Wh, written b-major [b*64+s][h]
    k_gemm<<<dim3(HH / 128, RT / 128), blk, 0, stream>>>(2, 512, 2, 512, RT, HH, 512, 3, nullptr, 2);
    k_rst<<<1, blk, 0, stream>>>(att_v);
    // decoder (cooperative, 96 blocks)
    hipLaunchCooperativeKernel((const void*)k_decoder, dim3(96), dim3(256), eargs, 0, stream);
    // logits GEMM straight into d_out (+bias, (t,b)->(b,t) remap)
    k_gemm_big<<<(VT / 128) * (RT / 128), blk, 0, stream>>>(h2o_b, out);
    k_lsm<<<RT, blk, 0, stream>>>(out);
}

// Round 5
// 4076.314 us; speedup vs baseline: 2.2650x; 1.0260x over previous
//
#include <hip/hip_runtime.h>
#include <hip/hip_bf16.h>
#include <math.h>

#define BB 64
#define LL 64
#define EE 512
#define HH 512
#define G4 2048
#define VT 32000
#define RT 4096  // LL*BB

typedef unsigned short u16;
typedef unsigned int u32;
typedef __attribute__((ext_vector_type(8))) unsigned short ushort8;
typedef __attribute__((ext_vector_type(8))) short bf16x8;
typedef __attribute__((ext_vector_type(4))) float f32x4;

// ---------------- static device scratch ----------------
__device__ u16   gW2T[(size_t)VT * 1024];   // h2o_W^T (VT x 1024) bf16
__device__ u16   gEncWxT[G4 * EE];
__device__ u16   gEncWhT[G4 * HH];
__device__ u16   gAttWhT[HH * HH];
__device__ u16   gDecWxTe[G4 * EE];
__device__ u16   gDecWxTc[G4 * HH];
__device__ u16   gDecWhT[G4 * HH];
__device__ u16   gWsB[HH * HH];             // att_Ws bf16, ORIGINAL [k][c] layout
__device__ u16   gSrcEmb[RT * EE];
__device__ u16   gTgtEmb[RT * EE];
__device__ float gXWxE[(size_t)RT * G4];    // src_emb @ enc_Wx + enc_b
__device__ float gXWxD[(size_t)RT * G4];    // tgt_emb @ dec_Wx[:512] + dec_b
__device__ u16   gEncHb[(size_t)RT * HH];   // enc h bf16, [t*64+b][h]
__device__ u16   gEncHb2[(size_t)RT * HH];  // enc h bf16, [b*64+t][h]
__device__ float gEncT[(size_t)RT * HH];    // enc_hiddens @ att_Wh, [b*64+s][h]
__device__ u16   gHcat[(size_t)RT * 1024];  // [h | ctx] bf16, row rr=t*64+b
__device__ float gC[BB * HH];               // LSTM cell state
__device__ float gAv[HH];
__device__ unsigned gBar;

__device__ __forceinline__ u16 f2b(float f) {
    union { float f; unsigned u; } v{f};
    unsigned r = v.u + 0x7fffu + ((v.u >> 16) & 1u);
    return (u16)(r >> 16);
}
__device__ __forceinline__ float b2f(u16 x) {
    union { unsigned u; float f; } v; v.u = ((unsigned)x) << 16; return v.f;
}
__device__ __forceinline__ float sigm(float x) { return 1.f / (1.f + __expf(-x)); }
__device__ __forceinline__ float ftanh(float x) {
    x = fminf(15.f, fmaxf(-15.f, x));
    float e = __expf(2.f * x);
    return (e - 1.f) / (e + 1.f);
}

// ---- L2-bypass (MALL-coherent) memory helpers: no cache-maintenance ops ----
__device__ __forceinline__ void ld16(const void* addr, bf16x8* a) {
    asm volatile(
        "global_load_dwordx4 %0, %16, off sc0 sc1\n\t"
        "global_load_dwordx4 %1, %16, off offset:64 sc0 sc1\n\t"
        "global_load_dwordx4 %2, %16, off offset:128 sc0 sc1\n\t"
        "global_load_dwordx4 %3, %16, off offset:192 sc0 sc1\n\t"
        "global_load_dwordx4 %4, %16, off offset:256 sc0 sc1\n\t"
        "global_load_dwordx4 %5, %16, off offset:320 sc0 sc1\n\t"
        "global_load_dwordx4 %6, %16, off offset:384 sc0 sc1\n\t"
        "global_load_dwordx4 %7, %16, off offset:448 sc0 sc1\n\t"
        "global_load_dwordx4 %8, %16, off offset:512 sc0 sc1\n\t"
        "global_load_dwordx4 %9, %16, off offset:576 sc0 sc1\n\t"
        "global_load_dwordx4 %10, %16, off offset:640 sc0 sc1\n\t"
        "global_load_dwordx4 %11, %16, off offset:704 sc0 sc1\n\t"
        "global_load_dwordx4 %12, %16, off offset:768 sc0 sc1\n\t"
        "global_load_dwordx4 %13, %16, off offset:832 sc0 sc1\n\t"
        "global_load_dwordx4 %14, %16, off offset:896 sc0 sc1\n\t"
        "global_load_dwordx4 %15, %16, off offset:960 sc0 sc1\n\t"
        "s_waitcnt vmcnt(0)"
        : "=&v"(a[0]), "=&v"(a[1]), "=&v"(a[2]), "=&v"(a[3]),
          "=&v"(a[4]), "=&v"(a[5]), "=&v"(a[6]), "=&v"(a[7]),
          "=&v"(a[8]), "=&v"(a[9]), "=&v"(a[10]), "=&v"(a[11]),
          "=&v"(a[12]), "=&v"(a[13]), "=&v"(a[14]), "=&v"(a[15])
        : "v"(addr) : "memory");
}
__device__ __forceinline__ u32 ld1(const void* addr) {
    u32 r;
    asm volatile("global_load_dword %0, %1, off sc0 sc1\n\ts_waitcnt vmcnt(0)"
                 : "=&v"(r) : "v"(addr) : "memory");
    return r;
}
__device__ __forceinline__ void st16b(u16* p, u16 v) {
    u32 vv = v;
    asm volatile("global_store_short %0, %1, off sc0 sc1" :: "v"(p), "v"(vv) : "memory");
}
__device__ __forceinline__ void st32b(u32* p, u32 v) {
    asm volatile("global_store_dword %0, %1, off sc0 sc1" :: "v"(p), "v"(v) : "memory");
}

// grid barrier: per-thread store drain, RELAXED system-scope arrive+spin (no cache ops)
__device__ __forceinline__ void gsyncS(unsigned nb, unsigned& gen) {
    asm volatile("s_waitcnt vmcnt(0)" ::: "memory");
    __syncthreads();
    if (threadIdx.x == 0) {
        gen += nb;
        __hip_atomic_fetch_add(&gBar, 1u, __ATOMIC_RELAXED, __HIP_MEMORY_SCOPE_SYSTEM);
        while (__hip_atomic_load(&gBar, __ATOMIC_RELAXED, __HIP_MEMORY_SCOPE_SYSTEM) < gen)
            __builtin_amdgcn_s_sleep(1);
    }
    __syncthreads();
}

__device__ __forceinline__ void g2l16(const u16* g, u16* l) {
    __builtin_amdgcn_global_load_lds(
        (const __attribute__((address_space(1))) unsigned int*)g,
        (__attribute__((address_space(3))) unsigned int*)l, 16, 0, 0);
}

// ---------------- transpose fp32 (R x C) -> bf16 (C x R) ----------------
__device__ inline u16* bf16sel(int s) {
    switch (s) {
        case 0: return gW2T;    case 1: return gEncWxT; case 2: return gEncWhT;
        case 3: return gAttWhT; case 4: return gDecWxTe; case 5: return gDecWxTc;
        default: return gDecWhT;
    }
}

__global__ __launch_bounds__(256) void k_transpose(const float* __restrict__ in, int R, int C, int sel) {
    __shared__ float tile[32][33];
    int tx = threadIdx.x & 31, ty0 = threadIdx.x >> 5;
    int c0 = blockIdx.x * 32, r0 = blockIdx.y * 32;
#pragma unroll
    for (int k = 0; k < 4; k++) {
        int ty = ty0 + k * 8;
        tile[ty][tx] = in[(size_t)(r0 + ty) * C + c0 + tx];
    }
    __syncthreads();
    u16* out = bf16sel(sel);
#pragma unroll
    for (int k = 0; k < 4; k++) {
        int ty = ty0 + k * 8;
        out[(size_t)(c0 + ty) * R + r0 + tx] = f2b(tile[tx][ty]);
    }
}

__global__ __launch_bounds__(256) void k_tobf(const float* __restrict__ in) {
    int i = blockIdx.x * 256 + threadIdx.x;
    gWsB[i] = f2b(in[i]);
}

__global__ __launch_bounds__(256) void k_gather(const int* __restrict__ tok, const float* __restrict__ tab, int sel) {
    int r = blockIdx.x;
    int b = r & 63, t = r >> 6;
    int token = tok[b * LL + t];
    u16* dst = (sel == 0) ? gSrcEmb : gTgtEmb;
    const float* srow = tab + (size_t)token * EE;
    for (int e = threadIdx.x; e < EE; e += 256)
        dst[(size_t)r * EE + e] = f2b(srow[e]);
}

__global__ __launch_bounds__(256) void k_zero() {
    int i = blockIdx.x * 256 + threadIdx.x;  // 128 blocks
    gC[i] = 0.f;
    if (i == 0) gBar = 0u;
}

__global__ __launch_bounds__(256) void k_rst(const float* __restrict__ av) {
    int t = threadIdx.x;
    gAv[t] = av[t];
    gAv[t + 256] = av[t + 256];
    if (t == 0) gBar = 0u;
}

// ---------------- generic bf16 MFMA GEMM: C(MxN) = A(MxK) * B^T(NxK) ----------------
__global__ __launch_bounds__(256) void k_gemm(int selA, int lda, int selB, int ldb,
                                              int M, int N, int K, int epi,
                                              const float* __restrict__ bias, int selOut) {
    __shared__ u16 sA[128 * 72];
    __shared__ u16 sB[128 * 72];
    const u16* Ag;
    switch (selA) { case 0: Ag = gSrcEmb; break; case 1: Ag = gTgtEmb; break; default: Ag = gEncHb; }
    const u16* Bg;
    switch (selB) { case 0: Bg = gEncWxT; break; case 1: Bg = gDecWxTe; break; default: Bg = gAttWhT; }
    float* Cg;
    if (selOut == 0) Cg = gXWxE; else if (selOut == 1) Cg = gXWxD; else Cg = gEncT;

    int tid = threadIdx.x, l = tid & 63, wid = tid >> 6, wr = wid >> 1, wc = wid & 1;
    int ar = l & 15, ak = (l >> 4) * 8;
    int rowM = blockIdx.y * 128, colN = blockIdx.x * 128;
    f32x4 acc[4][4];
#pragma unroll
    for (int m = 0; m < 4; m++)
#pragma unroll
        for (int n = 0; n < 4; n++) acc[m][n] = (f32x4){0.f, 0.f, 0.f, 0.f};

    for (int k0 = 0; k0 < K; k0 += 64) {
#pragma unroll
        for (int it = 0; it < 4; it++) {
            int idx = it * 256 + tid;
            int row = idx >> 3, cc = idx & 7;
            *(ushort8*)(sA + row * 72 + cc * 8) =
                *(const ushort8*)(Ag + (size_t)(rowM + row) * lda + k0 + cc * 8);
            *(ushort8*)(sB + row * 72 + cc * 8) =
                *(const ushort8*)(Bg + (size_t)(colN + row) * ldb + k0 + cc * 8);
        }
        __syncthreads();
#pragma unroll
        for (int ks = 0; ks < 2; ks++) {
            bf16x8 a[4], b[4];
#pragma unroll
            for (int m = 0; m < 4; m++) a[m] = *(const bf16x8*)(sA + (wr * 64 + m * 16 + ar) * 72 + ks * 32 + ak);
#pragma unroll
            for (int n = 0; n < 4; n++) b[n] = *(const bf16x8*)(sB + (wc * 64 + n * 16 + ar) * 72 + ks * 32 + ak);
#pragma unroll
            for (int m = 0; m < 4; m++)
#pragma unroll
                for (int n = 0; n < 4; n++)
                    acc[m][n] = __builtin_amdgcn_mfma_f32_16x16x32_bf16(a[m], b[n], acc[m][n], 0, 0, 0);
        }
        __syncthreads();
    }
    int rb = (l >> 4) * 4;
#pragma unroll
    for (int m = 0; m < 4; m++)
#pragma unroll
        for (int n = 0; n < 4; n++)
#pragma unroll
            for (int ri = 0; ri < 4; ri++) {
                int row = rowM + wr * 64 + m * 16 + rb + ri;
                int col = colN + wc * 64 + n * 16 + ar;
                float v = acc[m][n][ri];
                if (epi == 2) Cg[(size_t)row * N + col] = v + bias[col];
                else Cg[(size_t)((row & 63) * 64 + (row >> 6)) * N + col] = v;
            }
}

// ---------------- logits GEMM (m97 structure + XCD swizzle) ----------------
__global__ __launch_bounds__(256) void k_gemm_big(const float* __restrict__ bias, float* __restrict__ out) {
    __shared__ u16 sA[128 * 64];
    __shared__ u16 sB[128 * 64];
    int tid = threadIdx.x, l = tid & 63, wid = tid >> 6, wr = wid >> 1, wc = wid & 1;
    int ar = l & 15, ak = (l >> 4) * 8, rb = (l >> 4) * 4;
    int bid = (blockIdx.x & 7) * 1000 + (blockIdx.x >> 3);  // 8000 blocks, XCD-chunked
    int bxx = bid % (VT / 128), byy = bid / (VT / 128);
    int rowM = byy * 128, colN = bxx * 128;
    f32x4 acc[4][4];
#pragma unroll
    for (int m = 0; m < 4; m++)
#pragma unroll
        for (int n = 0; n < 4; n++) acc[m][n] = (f32x4){0.f, 0.f, 0.f, 0.f};

    int srow = wid * 32 + (l >> 3);
    int scol = (l & 7) * 8;
    for (int k0 = 0; k0 < 1024; k0 += 64) {
#pragma unroll
        for (int c = 0; c < 4; c++) {
            int r = srow + c * 8;
            g2l16(gHcat + (size_t)(rowM + r) * 1024 + k0 + scol, sA + r * 64 + scol);
            g2l16(gW2T + (size_t)(colN + r) * 1024 + k0 + scol, sB + r * 64 + scol);
        }
        __syncthreads();
#pragma unroll
        for (int ks = 0; ks < 2; ks++) {
            bf16x8 a[4], b[4];
#pragma unroll
            for (int m = 0; m < 4; m++) a[m] = *(const bf16x8*)(sA + (wr * 64 + m * 16 + ar) * 64 + ks * 32 + ak);
#pragma unroll
            for (int n = 0; n < 4; n++) b[n] = *(const bf16x8*)(sB + (wc * 64 + n * 16 + ar) * 64 + ks * 32 + ak);
#pragma unroll
            for (int m = 0; m < 4; m++)
#pragma unroll
                for (int n = 0; n < 4; n++)
                    acc[m][n] = __builtin_amdgcn_mfma_f32_16x16x32_bf16(a[m], b[n], acc[m][n], 0, 0, 0);
        }
        __syncthreads();
    }
#pragma unroll
    for (int m = 0; m < 4; m++)
#pragma unroll
        for (int n = 0; n < 4; n++)
#pragma unroll
            for (int ri = 0; ri < 4; ri++) {
                int row = rowM + wr * 64 + m * 16 + rb + ri;
                int col = colN + wc * 64 + n * 16 + ar;
                out[(size_t)((row & 63) * 64 + (row >> 6)) * VT + col] = acc[m][n][ri] + bias[col];
            }
}

// ---------------- encoder: 32 blocks, 16 h-cols each, 1 barrier/step ----------------
__global__ __launch_bounds__(256) void k_encoder(int dummy) {
    __shared__ u16 sW[64 * 512];  // 64 rows (g*16+c) x 512 K, XOR-swizzled, 64KB
    int tid = threadIdx.x, l = tid & 63, wid = tid >> 6;
    int j = blockIdx.x;  // h-cols [16j, 16j+16)
#pragma unroll
    for (int it = 0; it < 16; it++) {
        int idx = it * 256 + tid;
        int lr = idx >> 6, kc = idx & 63;
        int gcol = (lr >> 4) * 512 + j * 16 + (lr & 15);
        int off = (lr * 1024 + kc * 16) ^ ((lr & 7) << 4);
        *(ushort8*)((char*)sW + off) = *(const ushort8*)(gEncWhT + (size_t)gcol * 512 + kc * 8);
    }
    __syncthreads();
    int ar = l & 15, ak = (l >> 4) * 8, rb = (l >> 4) * 4;
    int arow = wid * 16 + ar, aoff = (l >> 4) * 16;
    unsigned gen = 0;
    for (int t = 0; t < LL; t++) {
        f32x4 acc[4];
#pragma unroll
        for (int g = 0; g < 4; g++) acc[g] = (f32x4){0.f, 0.f, 0.f, 0.f};
        if (t > 0) {
            bf16x8 af[16];
            ld16((const char*)gEncHb + (size_t)((t - 1) * BB + arow) * 1024 + aoff, af);
#pragma unroll
            for (int kk = 0; kk < 16; kk++) {
                int k = kk * 32 + ak;
#pragma unroll
                for (int g = 0; g < 4; g++) {
                    int lr = g * 16 + ar;
                    bf16x8 b = *(const bf16x8*)((char*)sW + ((lr * 1024 + k * 2) ^ ((lr & 7) << 4)));
                    acc[g] = __builtin_amdgcn_mfma_f32_16x16x32_bf16(af[kk], b, acc[g], 0, 0, 0);
                }
            }
        }
        int hcol = j * 16 + ar;
#pragma unroll
        for (int ri = 0; ri < 4; ri++) {
            int row = wid * 16 + rb + ri;
            int rr = t * BB + row;
            const float* xw = gXWxE + (size_t)rr * G4;
            float zi = acc[0][ri] + xw[hcol];
            float zf = acc[1][ri] + xw[512 + hcol];
            float zg = acc[2][ri] + xw[1024 + hcol];
            float zo = acc[3][ri] + xw[1536 + hcol];
            float co = gC[row * HH + hcol];
            float cn = sigm(zf) * co + sigm(zi) * ftanh(zg);
            float hn = sigm(zo) * ftanh(cn);
            gC[row * HH + hcol] = cn;
            u16 hb = f2b(hn);
            st16b(gEncHb + (size_t)rr * HH + hcol, hb);
            gEncHb2[(size_t)(row * LL + t) * HH + hcol] = hb;  // next-kernel only
        }
        gsyncS(32, gen);
    }
}

// ---------------- decoder: 96 blocks (64 attention + 32 GEMM), 2 barriers/step ----------------
__global__ __launch_bounds__(256) void k_decoder(int dummy) {
    __shared__ u16 sWh[64 * 512];   // dec_Wh slice, 64KB
    __shared__ u16 sWx[64 * 512];   // dec_Wx[512:] slice, 64KB
    __shared__ float s_h[512];
    __shared__ float s_dt[512];
    __shared__ float s_av[512];
    __shared__ float s_att[64];
    __shared__ float s_red[256];
    __shared__ float s_mv[4][520];
    int tid = threadIdx.x, l = tid & 63, wid = tid >> 6;
    int bx = blockIdx.x;
    int ar = l & 15, ak = (l >> 4) * 8, rb = (l >> 4) * 4;
    int arow = wid * 16 + ar, aoff = (l >> 4) * 16;
    if (bx >= 64) {
        int j = bx - 64;  // h-cols [16j, 16j+16)
#pragma unroll
        for (int it = 0; it < 16; it++) {
            int idx = it * 256 + tid;
            int lr = idx >> 6, kc = idx & 63;
            int gcol = (lr >> 4) * 512 + j * 16 + (lr & 15);
            int off = (lr * 1024 + kc * 16) ^ ((lr & 7) << 4);
            *(ushort8*)((char*)sWh + off) = *(const ushort8*)(gDecWhT + (size_t)gcol * 512 + kc * 8);
            *(ushort8*)((char*)sWx + off) = *(const ushort8*)(gDecWxTc + (size_t)gcol * 512 + kc * 8);
        }
    } else {
        s_av[tid] = gAv[tid];
        s_av[tid + 256] = gAv[tid + 256];
    }
    __syncthreads();
    unsigned gen = 0;
    for (int t = 0; t < LL; t++) {
        f32x4 acc[4];
#pragma unroll
        for (int g = 0; g < 4; g++) acc[g] = (f32x4){0.f, 0.f, 0.f, 0.f};
        if (bx < 64) {
            // ======== attention for batch row b ========
            int b = bx;
            const char* hb = (t == 0) ? ((const char*)gEncHb + (size_t)(63 * BB + b) * 1024)
                                      : ((const char*)gHcat + (size_t)((t - 1) * BB + b) * 2048);
            u32 hw = ld1(hb + 4 * tid);
            s_h[2 * tid] = b2f((u16)(hw & 0xffff));
            s_h[2 * tid + 1] = b2f((u16)(hw >> 16));
            __syncthreads();
            // dec_t = h @ att_Ws: thread (kq, c8): cols [8c8,8c8+8), k in [128kq,128kq+128)
            {
                int c8 = tid & 63, kq = tid >> 6;
                float a8[8];
#pragma unroll
                for (int jj = 0; jj < 8; jj++) a8[jj] = 0.f;
                const u16* wp = gWsB + (size_t)(kq * 128) * 512 + c8 * 8;
#pragma unroll 4
                for (int i = 0; i < 128; i++) {
                    ushort8 w = *(const ushort8*)(wp + (size_t)i * 512);
                    float hk = s_h[kq * 128 + i];
#pragma unroll
                    for (int jj = 0; jj < 8; jj++) a8[jj] += hk * b2f((u16)w[jj]);
                }
#pragma unroll
                for (int jj = 0; jj < 8; jj++) s_mv[kq][c8 * 8 + jj] = a8[jj];
            }
            __syncthreads();
            {
                float d0 = s_mv[0][tid] + s_mv[1][tid] + s_mv[2][tid] + s_mv[3][tid];
                float d1 = s_mv[0][tid + 256] + s_mv[1][tid + 256] + s_mv[2][tid + 256] + s_mv[3][tid + 256];
                s_dt[tid] = d0;
                s_dt[tid + 256] = d1;
            }
            __syncthreads();
            // energy
            int s = tid >> 2, q = tid & 3;
            const float* et = gEncT + (size_t)(b * LL + s) * HH;
            float p = 0.f;
#pragma unroll 4
            for (int i = 0; i < 128; i++) {
                int h = i * 4 + q;
                p += ftanh(et[h] + s_dt[h]) * s_av[h];
            }
            s_red[tid] = p;
            __syncthreads();
            if (tid < 64) {
                float v = s_red[tid * 4] + s_red[tid * 4 + 1] + s_red[tid * 4 + 2] + s_red[tid * 4 + 3];
                float m = v;
                for (int o = 32; o; o >>= 1) m = fmaxf(m, __shfl_xor(m, o));
                float e = __expf(v - m);
                float ss = e;
                for (int o = 32; o; o >>= 1) ss += __shfl_xor(ss, o);
                s_att[tid] = e / ss;
            }
            __syncthreads();
            // context -> ctx half of gHcat (bypass store)
            int c = tid * 2;
            float c0 = 0.f, c1 = 0.f;
            const u16* eh = gEncHb2 + (size_t)b * LL * HH;
#pragma unroll 8
            for (int s2 = 0; s2 < 64; s2++) {
                float a = s_att[s2];
                u32 w = *(const u32*)(eh + (size_t)s2 * HH + c);
                c0 += a * b2f((u16)(w & 0xffff));
                c1 += a * b2f((u16)(w >> 16));
            }
            u32 cw = (u32)f2b(c0) | ((u32)f2b(c1) << 16);
            st32b((u32*)(gHcat + (size_t)(t * BB + b) * 1024 + 512 + c), cw);
        } else {
            // ======== GEMM phase A: acc = h_prev @ Wh_slice ========
            bf16x8 af[16];
            const char* baseA = (t == 0)
                ? ((const char*)gEncHb + (size_t)(63 * BB + arow) * 1024 + aoff)
                : ((const char*)gHcat + (size_t)((t - 1) * BB + arow) * 2048 + aoff);
            ld16(baseA, af);
#pragma unroll
            for (int kk = 0; kk < 16; kk++) {
                int k = kk * 32 + ak;
#pragma unroll
                for (int g = 0; g < 4; g++) {
                    int lr = g * 16 + ar;
                    bf16x8 b = *(const bf16x8*)((char*)sWh + ((lr * 1024 + k * 2) ^ ((lr & 7) << 4)));
                    acc[g] = __builtin_amdgcn_mfma_f32_16x16x32_bf16(af[kk], b, acc[g], 0, 0, 0);
                }
            }
        }
        gsyncS(96, gen);  // SYNC1: ctx visible
        if (bx >= 64) {
            int j = bx - 64;
            // ======== GEMM phase B: acc += ctx @ WxC_slice; gates; write h ========
            bf16x8 cf[16];
            ld16((const char*)gHcat + (size_t)(t * BB + arow) * 2048 + 1024 + aoff, cf);
#pragma unroll
            for (int kk = 0; kk < 16; kk++) {
                int k = kk * 32 + ak;
#pragma unroll
                for (int g = 0; g < 4; g++) {
                    int lr = g * 16 + ar;
                    bf16x8 b = *(const bf16x8*)((char*)sWx + ((lr * 1024 + k * 2) ^ ((lr & 7) << 4)));
                    acc[g] = __builtin_amdgcn_mfma_f32_16x16x32_bf16(cf[kk], b, acc[g], 0, 0, 0);
                }
            }
            int hcol = j * 16 + ar;
#pragma unroll
            for (int ri = 0; ri < 4; ri++) {
                int row = wid * 16 + rb + ri;
                int rr = t * BB + row;
                const float* xw = gXWxD + (size_t)rr * G4;
                float zi = acc[0][ri] + xw[hcol];
                float zf = acc[1][ri] + xw[512 + hcol];
                float zg = acc[2][ri] + xw[1024 + hcol];
                float zo = acc[3][ri] + xw[1536 + hcol];
                float co = gC[row * HH + hcol];
                float cn = sigm(zf) * co + sigm(zi) * ftanh(zg);
                float hn = sigm(zo) * ftanh(cn);
                gC[row * HH + hcol] = cn;
                st16b(gHcat + (size_t)rr * 1024 + hcol, f2b(hn));
            }
        }
        gsyncS(96, gen);  // SYNC2: h_t visible
    }
}

// ---------------- log-softmax in place, online max/sum, float4 ----------------
__global__ __launch_bounds__(256) void k_lsm(float* __restrict__ out) {
    int row = blockIdx.x, tid = threadIdx.x;
    float4* p4 = (float4*)(out + (size_t)row * VT);
    float m = -1e30f, s = 0.f;
    for (int i = tid; i < VT / 4; i += 256) {
        float4 v = p4[i];
        float mx = fmaxf(fmaxf(v.x, v.y), fmaxf(v.z, v.w));
        float mn = fmaxf(m, mx);
        s = s * __expf(m - mn) + __expf(v.x - mn) + __expf(v.y - mn) + __expf(v.z - mn) + __expf(v.w - mn);
        m = mn;
    }
    for (int o = 32; o; o >>= 1) {
        float m2 = __shfl_xor(m, o), s2 = __shfl_xor(s, o);
        float mn = fmaxf(m, m2);
        s = s * __expf(m - mn) + s2 * __expf(m2 - mn);
        m = mn;
    }
    __shared__ float rm[4], rs[4];
    if ((tid & 63) == 0) { rm[tid >> 6] = m; rs[tid >> 6] = s; }
    __syncthreads();
    float mm = fmaxf(fmaxf(rm[0], rm[1]), fmaxf(rm[2], rm[3]));
    float ss = rs[0] * __expf(rm[0] - mm) + rs[1] * __expf(rm[1] - mm) +
               rs[2] * __expf(rm[2] - mm) + rs[3] * __expf(rm[3] - mm);
    float lse = mm + __logf(ss);
    for (int i = tid; i < VT / 4; i += 256) {
        float4 v = p4[i];
        v.x -= lse; v.y -= lse; v.z -= lse; v.w -= lse;
        p4[i] = v;
    }
}

extern "C" void kernel_launch(void* const* d_in, const int* in_sizes, int n_in,
                              void* d_out, int out_size, void* d_ws, size_t ws_size,
                              hipStream_t stream) {
    const int*   src       = (const int*)d_in[0];
    const int*   tgt       = (const int*)d_in[1];
    const float* src_embed = (const float*)d_in[2];
    const float* enc_Wx    = (const float*)d_in[3];
    const float* enc_Wh    = (const float*)d_in[4];
    const float* enc_b     = (const float*)d_in[5];
    const float* tgt_embed = (const float*)d_in[6];
    const float* att_Wh    = (const float*)d_in[7];
    const float* att_Ws    = (const float*)d_in[8];
    const float* att_v     = (const float*)d_in[9];
    const float* dec_Wx    = (const float*)d_in[10];
    const float* dec_Wh    = (const float*)d_in[11];
    const float* dec_b     = (const float*)d_in[12];
    const float* h2o_W     = (const float*)d_in[13];
    const float* h2o_b     = (const float*)d_in[14];
    float* out = (float*)d_out;
    dim3 blk(256);

    k_transpose<<<dim3(VT / 32, 1024 / 32), blk, 0, stream>>>(h2o_W, 1024, VT, 0);
    k_transpose<<<dim3(G4 / 32, EE / 32), blk, 0, stream>>>(enc_Wx, EE, G4, 1);
    k_transpose<<<dim3(G4 / 32, HH / 32), blk, 0, stream>>>(enc_Wh, HH, G4, 2);
    k_transpose<<<dim3(HH / 32, HH / 32), blk, 0, stream>>>(att_Wh, HH, HH, 3);
    k_transpose<<<dim3(G4 / 32, EE / 32), blk, 0, stream>>>(dec_Wx, EE, G4, 4);
    k_transpose<<<dim3(G4 / 32, HH / 32), blk, 0, stream>>>(dec_Wx + (size_t)512 * G4, HH, G4, 5);
    k_transpose<<<dim3(G4 / 32, HH / 32), blk, 0, stream>>>(dec_Wh, HH, G4, 6);
    k_tobf<<<HH * HH / 256, blk, 0, stream>>>(att_Ws);
    k_gather<<<RT, blk, 0, stream>>>(src, src_embed, 0);
    k_gather<<<RT, blk, 0, stream>>>(tgt, tgt_embed, 1);
    k_zero<<<128, blk, 0, stream>>>();
    // hoisted input GEMMs (+bias folded)
    k_gemm<<<dim3(G4 / 128, RT / 128), blk, 0, stream>>>(0, 512, 0, 512, RT, G4, 512, 2, enc_b, 0);
    k_gemm<<<dim3(G4 / 128, RT / 128), blk, 0, stream>>>(1, 512, 1, 512, RT, G4, 512, 2, dec_b, 1);
    // encoder (cooperative, 32 blocks)
    int dummy = 0;
    void* eargs[] = { &dummy };
    hipLaunchCooperativeKernel((const void*)k_encoder, dim3(32), dim3(256), eargs, 0, stream);
    // enc_t = enc_hiddens @ att_Wh, written b-major [b*64+s][h]
    k_gemm<<<dim3(HH / 128, RT / 128), blk, 0, stream>>>(2, 512, 2, 512, RT, HH, 512, 3, nullptr, 2);
    k_rst<<<1, blk, 0, stream>>>(att_v);
    // decoder (cooperative, 96 blocks)
    hipLaunchCooperativeKernel((const void*)k_decoder, dim3(96), dim3(256), eargs, 0, stream);
    // logits GEMM straight into d_out (+bias, (t,b)->(b,t) remap)
    k_gemm_big<<<(VT / 128) * (RT / 128), blk, 0, stream>>>(h2o_b, out);
    k_lsm<<<RT, blk, 0, stream>>>(out);
}

// Round 6
// 3727.555 us; speedup vs baseline: 2.4769x; 1.0936x over previous
//
#include <hip/hip_runtime.h>
#include <hip/hip_bf16.h>
#include <math.h>

#define BB 64
#define LL 64
#define EE 512
#define HH 512
#define G4 2048
#define VT 32000
#define RT 4096  // LL*BB

typedef unsigned short u16;
typedef unsigned int u32;
typedef __attribute__((ext_vector_type(8))) unsigned short ushort8;
typedef __attribute__((ext_vector_type(8))) short bf16x8;
typedef __attribute__((ext_vector_type(4))) float f32x4;

// ---------------- static device scratch ----------------
__device__ u16   gW2T[(size_t)VT * 1024];   // h2o_W^T (VT x 1024) bf16
__device__ u16   gEncWxT[G4 * EE];
__device__ u16   gEncWhT[G4 * HH];
__device__ u16   gAttWhT[HH * HH];
__device__ u16   gAttWsT[HH * HH];          // att_Ws^T [c][k]
__device__ u16   gDecWxTe[G4 * EE];
__device__ u16   gDecWxTc[G4 * HH];
__device__ u16   gDecWhT[G4 * HH];
__device__ u16   gSrcEmb[RT * EE];
__device__ u16   gTgtEmb[RT * EE];
__device__ float gXWxE[(size_t)RT * G4];    // src_emb @ enc_Wx + enc_b
__device__ float gXWxD[(size_t)RT * G4];    // tgt_emb @ dec_Wx[:512] + dec_b
__device__ u16   gEncHb[(size_t)RT * HH];   // enc h bf16, [t*64+b][h]
__device__ u16   gEncHb2[(size_t)RT * HH];  // enc h bf16, [b*64+t][h]
__device__ float gEncT[(size_t)RT * HH];    // enc_hiddens @ att_Wh, [b*64+s][h]
__device__ u16   gHcat[(size_t)RT * 1024];  // [h | ctx] bf16, row rr=t*64+b
__device__ float gDecT[BB * HH];            // h_prev @ att_Ws (per step)
__device__ float gC[BB * HH];               // LSTM cell state
__device__ float gAv[HH];
__device__ unsigned gFlagE[64];             // encoder: per-block h-ready generation
__device__ unsigned gFlagA[64];             // decoder: dec_t ready (32 used)
__device__ unsigned gFlagB[64];             // decoder: ctx ready (64 used)
__device__ unsigned gFlagC[64];             // decoder: h ready (32 used)

__device__ __forceinline__ u16 f2b(float f) {
    union { float f; unsigned u; } v{f};
    unsigned r = v.u + 0x7fffu + ((v.u >> 16) & 1u);
    return (u16)(r >> 16);
}
__device__ __forceinline__ float b2f(u16 x) {
    union { unsigned u; float f; } v; v.u = ((unsigned)x) << 16; return v.f;
}
__device__ __forceinline__ float sigm(float x) { return 1.f / (1.f + __expf(-x)); }
__device__ __forceinline__ float ftanh(float x) {
    x = fminf(15.f, fmaxf(-15.f, x));
    float e = __expf(2.f * x);
    return (e - 1.f) / (e + 1.f);
}

// ---- L2-bypass (MALL-coherent) memory helpers ----
__device__ __forceinline__ void ld16(const void* addr, bf16x8* a) {
    asm volatile(
        "global_load_dwordx4 %0, %16, off sc0 sc1\n\t"
        "global_load_dwordx4 %1, %16, off offset:64 sc0 sc1\n\t"
        "global_load_dwordx4 %2, %16, off offset:128 sc0 sc1\n\t"
        "global_load_dwordx4 %3, %16, off offset:192 sc0 sc1\n\t"
        "global_load_dwordx4 %4, %16, off offset:256 sc0 sc1\n\t"
        "global_load_dwordx4 %5, %16, off offset:320 sc0 sc1\n\t"
        "global_load_dwordx4 %6, %16, off offset:384 sc0 sc1\n\t"
        "global_load_dwordx4 %7, %16, off offset:448 sc0 sc1\n\t"
        "global_load_dwordx4 %8, %16, off offset:512 sc0 sc1\n\t"
        "global_load_dwordx4 %9, %16, off offset:576 sc0 sc1\n\t"
        "global_load_dwordx4 %10, %16, off offset:640 sc0 sc1\n\t"
        "global_load_dwordx4 %11, %16, off offset:704 sc0 sc1\n\t"
        "global_load_dwordx4 %12, %16, off offset:768 sc0 sc1\n\t"
        "global_load_dwordx4 %13, %16, off offset:832 sc0 sc1\n\t"
        "global_load_dwordx4 %14, %16, off offset:896 sc0 sc1\n\t"
        "global_load_dwordx4 %15, %16, off offset:960 sc0 sc1\n\t"
        "s_waitcnt vmcnt(0)"
        : "=&v"(a[0]), "=&v"(a[1]), "=&v"(a[2]), "=&v"(a[3]),
          "=&v"(a[4]), "=&v"(a[5]), "=&v"(a[6]), "=&v"(a[7]),
          "=&v"(a[8]), "=&v"(a[9]), "=&v"(a[10]), "=&v"(a[11]),
          "=&v"(a[12]), "=&v"(a[13]), "=&v"(a[14]), "=&v"(a[15])
        : "v"(addr) : "memory");
}
__device__ __forceinline__ u32 ld1(const void* addr) {
    u32 r;
    asm volatile("global_load_dword %0, %1, off sc0 sc1\n\ts_waitcnt vmcnt(0)"
                 : "=&v"(r) : "v"(addr) : "memory");
    return r;
}
__device__ __forceinline__ float ldf(const float* p) {
    float r;
    asm volatile("global_load_dword %0, %1, off sc0 sc1\n\ts_waitcnt vmcnt(0)"
                 : "=&v"(r) : "v"(p) : "memory");
    return r;
}
__device__ __forceinline__ void st16b(u16* p, u16 v) {
    u32 vv = v;
    asm volatile("global_store_short %0, %1, off sc0 sc1" :: "v"(p), "v"(vv) : "memory");
}
__device__ __forceinline__ void st32b(u32* p, u32 v) {
    asm volatile("global_store_dword %0, %1, off sc0 sc1" :: "v"(p), "v"(v) : "memory");
}
__device__ __forceinline__ void stf(float* p, float v) {
    asm volatile("global_store_dword %0, %1, off sc0 sc1" :: "v"(p), "v"(v) : "memory");
}

// set this block's flag after all its data stores have completed at the coherence point
__device__ __forceinline__ void setflag(unsigned* f, unsigned v) {
    asm volatile("s_waitcnt vmcnt(0)" ::: "memory");  // every thread drains its stores
    __syncthreads();
    if (threadIdx.x == 0) st32b((u32*)f, v);
}
// wait until flags[0..n) all >= target (n power of two <= 64); wave 0 polls, one load per retry
__device__ __forceinline__ void waitflags(unsigned* flags, int n, unsigned target) {
    if (threadIdx.x < 64) {
        const unsigned* p = flags + (threadIdx.x & (n - 1));
        for (;;) {
            u32 v = ld1(p);
            if (__all(v >= target)) break;
            __builtin_amdgcn_s_sleep(1);
        }
    }
    __syncthreads();
}

__device__ __forceinline__ void g2l16(const u16* g, u16* l) {
    __builtin_amdgcn_global_load_lds(
        (const __attribute__((address_space(1))) unsigned int*)g,
        (__attribute__((address_space(3))) unsigned int*)l, 16, 0, 0);
}

// ---------------- transpose fp32 (R x C) -> bf16 (C x R) ----------------
__device__ inline u16* bf16sel(int s) {
    switch (s) {
        case 0: return gW2T;    case 1: return gEncWxT; case 2: return gEncWhT;
        case 3: return gAttWhT; case 4: return gDecWxTe; case 5: return gDecWxTc;
        case 6: return gDecWhT; default: return gAttWsT;
    }
}

__global__ __launch_bounds__(256) void k_transpose(const float* __restrict__ in, int R, int C, int sel) {
    __shared__ float tile[32][33];
    int tx = threadIdx.x & 31, ty0 = threadIdx.x >> 5;
    int c0 = blockIdx.x * 32, r0 = blockIdx.y * 32;
#pragma unroll
    for (int k = 0; k < 4; k++) {
        int ty = ty0 + k * 8;
        tile[ty][tx] = in[(size_t)(r0 + ty) * C + c0 + tx];
    }
    __syncthreads();
    u16* out = bf16sel(sel);
#pragma unroll
    for (int k = 0; k < 4; k++) {
        int ty = ty0 + k * 8;
        out[(size_t)(c0 + ty) * R + r0 + tx] = f2b(tile[tx][ty]);
    }
}

__global__ __launch_bounds__(256) void k_gather(const int* __restrict__ tok, const float* __restrict__ tab, int sel) {
    int r = blockIdx.x;
    int b = r & 63, t = r >> 6;
    int token = tok[b * LL + t];
    u16* dst = (sel == 0) ? gSrcEmb : gTgtEmb;
    const float* srow = tab + (size_t)token * EE;
    for (int e = threadIdx.x; e < EE; e += 256)
        dst[(size_t)r * EE + e] = f2b(srow[e]);
}

__global__ __launch_bounds__(256) void k_zero() {
    int i = blockIdx.x * 256 + threadIdx.x;  // 128 blocks
    gC[i] = 0.f;
    if (i < 64) {
        st32b((u32*)(gFlagE + i), 0u);
        st32b((u32*)(gFlagA + i), 0u);
        st32b((u32*)(gFlagB + i), 0u);
        st32b((u32*)(gFlagC + i), 0u);
    }
}

__global__ __launch_bounds__(256) void k_rst(const float* __restrict__ av) {
    int t = threadIdx.x;
    gAv[t] = av[t];
    gAv[t + 256] = av[t + 256];
}

// ---------------- generic bf16 MFMA GEMM: C(MxN) = A(MxK) * B^T(NxK) ----------------
__global__ __launch_bounds__(256) void k_gemm(int selA, int lda, int selB, int ldb,
                                              int M, int N, int K, int epi,
                                              const float* __restrict__ bias, int selOut) {
    __shared__ u16 sA[128 * 72];
    __shared__ u16 sB[128 * 72];
    const u16* Ag;
    switch (selA) { case 0: Ag = gSrcEmb; break; case 1: Ag = gTgtEmb; break; default: Ag = gEncHb; }
    const u16* Bg;
    switch (selB) { case 0: Bg = gEncWxT; break; case 1: Bg = gDecWxTe; break; default: Bg = gAttWhT; }
    float* Cg;
    if (selOut == 0) Cg = gXWxE; else if (selOut == 1) Cg = gXWxD; else Cg = gEncT;

    int tid = threadIdx.x, l = tid & 63, wid = tid >> 6, wr = wid >> 1, wc = wid & 1;
    int ar = l & 15, ak = (l >> 4) * 8;
    int rowM = blockIdx.y * 128, colN = blockIdx.x * 128;
    f32x4 acc[4][4];
#pragma unroll
    for (int m = 0; m < 4; m++)
#pragma unroll
        for (int n = 0; n < 4; n++) acc[m][n] = (f32x4){0.f, 0.f, 0.f, 0.f};

    for (int k0 = 0; k0 < K; k0 += 64) {
#pragma unroll
        for (int it = 0; it < 4; it++) {
            int idx = it * 256 + tid;
            int row = idx >> 3, cc = idx & 7;
            *(ushort8*)(sA + row * 72 + cc * 8) =
                *(const ushort8*)(Ag + (size_t)(rowM + row) * lda + k0 + cc * 8);
            *(ushort8*)(sB + row * 72 + cc * 8) =
                *(const ushort8*)(Bg + (size_t)(colN + row) * ldb + k0 + cc * 8);
        }
        __syncthreads();
#pragma unroll
        for (int ks = 0; ks < 2; ks++) {
            bf16x8 a[4], b[4];
#pragma unroll
            for (int m = 0; m < 4; m++) a[m] = *(const bf16x8*)(sA + (wr * 64 + m * 16 + ar) * 72 + ks * 32 + ak);
#pragma unroll
            for (int n = 0; n < 4; n++) b[n] = *(const bf16x8*)(sB + (wc * 64 + n * 16 + ar) * 72 + ks * 32 + ak);
#pragma unroll
            for (int m = 0; m < 4; m++)
#pragma unroll
                for (int n = 0; n < 4; n++)
                    acc[m][n] = __builtin_amdgcn_mfma_f32_16x16x32_bf16(a[m], b[n], acc[m][n], 0, 0, 0);
        }
        __syncthreads();
    }
    int rb = (l >> 4) * 4;
#pragma unroll
    for (int m = 0; m < 4; m++)
#pragma unroll
        for (int n = 0; n < 4; n++)
#pragma unroll
            for (int ri = 0; ri < 4; ri++) {
                int row = rowM + wr * 64 + m * 16 + rb + ri;
                int col = colN + wc * 64 + n * 16 + ar;
                float v = acc[m][n][ri];
                if (epi == 2) Cg[(size_t)row * N + col] = v + bias[col];
                else Cg[(size_t)((row & 63) * 64 + (row >> 6)) * N + col] = v;
            }
}

// ---------------- logits GEMM (m97 structure + XCD swizzle) ----------------
__global__ __launch_bounds__(256) void k_gemm_big(const float* __restrict__ bias, float* __restrict__ out) {
    __shared__ u16 sA[128 * 64];
    __shared__ u16 sB[128 * 64];
    int tid = threadIdx.x, l = tid & 63, wid = tid >> 6, wr = wid >> 1, wc = wid & 1;
    int ar = l & 15, ak = (l >> 4) * 8, rb = (l >> 4) * 4;
    int bid = (blockIdx.x & 7) * 1000 + (blockIdx.x >> 3);  // 8000 blocks, XCD-chunked
    int bxx = bid % (VT / 128), byy = bid / (VT / 128);
    int rowM = byy * 128, colN = bxx * 128;
    f32x4 acc[4][4];
#pragma unroll
    for (int m = 0; m < 4; m++)
#pragma unroll
        for (int n = 0; n < 4; n++) acc[m][n] = (f32x4){0.f, 0.f, 0.f, 0.f};

    int srow = wid * 32 + (l >> 3);
    int scol = (l & 7) * 8;
    for (int k0 = 0; k0 < 1024; k0 += 64) {
#pragma unroll
        for (int c = 0; c < 4; c++) {
            int r = srow + c * 8;
            g2l16(gHcat + (size_t)(rowM + r) * 1024 + k0 + scol, sA + r * 64 + scol);
            g2l16(gW2T + (size_t)(colN + r) * 1024 + k0 + scol, sB + r * 64 + scol);
        }
        __syncthreads();
#pragma unroll
        for (int ks = 0; ks < 2; ks++) {
            bf16x8 a[4], b[4];
#pragma unroll
            for (int m = 0; m < 4; m++) a[m] = *(const bf16x8*)(sA + (wr * 64 + m * 16 + ar) * 64 + ks * 32 + ak);
#pragma unroll
            for (int n = 0; n < 4; n++) b[n] = *(const bf16x8*)(sB + (wc * 64 + n * 16 + ar) * 64 + ks * 32 + ak);
#pragma unroll
            for (int m = 0; m < 4; m++)
#pragma unroll
                for (int n = 0; n < 4; n++)
                    acc[m][n] = __builtin_amdgcn_mfma_f32_16x16x32_bf16(a[m], b[n], acc[m][n], 0, 0, 0);
        }
        __syncthreads();
    }
#pragma unroll
    for (int m = 0; m < 4; m++)
#pragma unroll
        for (int n = 0; n < 4; n++)
#pragma unroll
            for (int ri = 0; ri < 4; ri++) {
                int row = rowM + wr * 64 + m * 16 + rb + ri;
                int col = colN + wc * 64 + n * 16 + ar;
                out[(size_t)((row & 63) * 64 + (row >> 6)) * VT + col] = acc[m][n][ri] + bias[col];
            }
}

// ---------------- encoder: 32 blocks, 16 h-cols each, flag sync ----------------
__global__ __launch_bounds__(256) void k_encoder(int dummy) {
    __shared__ u16 sW[64 * 512];  // 64 rows (g*16+c) x 512 K, XOR-swizzled, 64KB
    int tid = threadIdx.x, l = tid & 63, wid = tid >> 6;
    int j = blockIdx.x;  // h-cols [16j, 16j+16)
#pragma unroll
    for (int it = 0; it < 16; it++) {
        int idx = it * 256 + tid;
        int lr = idx >> 6, kc = idx & 63;
        int gcol = (lr >> 4) * 512 + j * 16 + (lr & 15);
        int off = (lr * 1024 + kc * 16) ^ ((lr & 7) << 4);
        *(ushort8*)((char*)sW + off) = *(const ushort8*)(gEncWhT + (size_t)gcol * 512 + kc * 8);
    }
    __syncthreads();
    int ar = l & 15, ak = (l >> 4) * 8, rb = (l >> 4) * 4;
    int arow = wid * 16 + ar, aoff = (l >> 4) * 16;
    for (int t = 0; t < LL; t++) {
        f32x4 acc[4];
#pragma unroll
        for (int g = 0; g < 4; g++) acc[g] = (f32x4){0.f, 0.f, 0.f, 0.f};
        if (t > 0) {
            waitflags(gFlagE, 32, (unsigned)t);
            bf16x8 af[16];
            ld16((const char*)gEncHb + (size_t)((t - 1) * BB + arow) * 1024 + aoff, af);
#pragma unroll
            for (int kk = 0; kk < 16; kk++) {
                int k = kk * 32 + ak;
#pragma unroll
                for (int g = 0; g < 4; g++) {
                    int lr = g * 16 + ar;
                    bf16x8 b = *(const bf16x8*)((char*)sW + ((lr * 1024 + k * 2) ^ ((lr & 7) << 4)));
                    acc[g] = __builtin_amdgcn_mfma_f32_16x16x32_bf16(af[kk], b, acc[g], 0, 0, 0);
                }
            }
        }
        int hcol = j * 16 + ar;
#pragma unroll
        for (int ri = 0; ri < 4; ri++) {
            int row = wid * 16 + rb + ri;
            int rr = t * BB + row;
            const float* xw = gXWxE + (size_t)rr * G4;
            float zi = acc[0][ri] + xw[hcol];
            float zf = acc[1][ri] + xw[512 + hcol];
            float zg = acc[2][ri] + xw[1024 + hcol];
            float zo = acc[3][ri] + xw[1536 + hcol];
            float co = gC[row * HH + hcol];
            float cn = sigm(zf) * co + sigm(zi) * ftanh(zg);
            float hn = sigm(zo) * ftanh(cn);
            gC[row * HH + hcol] = cn;
            u16 hb = f2b(hn);
            st16b(gEncHb + (size_t)rr * HH + hcol, hb);
            gEncHb2[(size_t)(row * LL + t) * HH + hcol] = hb;  // next-kernel only
        }
        setflag(gFlagE + j, (unsigned)(t + 1));
    }
}

// ---------------- decoder: 96 blocks (64 attention + 32 GEMM), flag sync ----------------
__global__ __launch_bounds__(256) void k_decoder(int dummy) {
    __shared__ u16 sWh[64 * 512];   // dec_Wh slice, 64KB
    __shared__ u16 sWx[64 * 512];   // dec_Wx[512:] slice, 64KB
    __shared__ u16 sWs[16 * 512];   // att_Ws^T slice, 16KB
    __shared__ float s_dt[512];
    __shared__ float s_av[512];
    __shared__ float s_att[64];
    __shared__ float s_red[256];
    int tid = threadIdx.x, l = tid & 63, wid = tid >> 6;
    int bx = blockIdx.x;
    int ar = l & 15, ak = (l >> 4) * 8, rb = (l >> 4) * 4;
    int arow = wid * 16 + ar, aoff = (l >> 4) * 16;
    if (bx >= 64) {
        int j = bx - 64;  // h-cols [16j, 16j+16)
#pragma unroll
        for (int it = 0; it < 16; it++) {
            int idx = it * 256 + tid;
            int lr = idx >> 6, kc = idx & 63;
            int gcol = (lr >> 4) * 512 + j * 16 + (lr & 15);
            int off = (lr * 1024 + kc * 16) ^ ((lr & 7) << 4);
            *(ushort8*)((char*)sWh + off) = *(const ushort8*)(gDecWhT + (size_t)gcol * 512 + kc * 8);
            *(ushort8*)((char*)sWx + off) = *(const ushort8*)(gDecWxTc + (size_t)gcol * 512 + kc * 8);
        }
#pragma unroll
        for (int it = 0; it < 4; it++) {
            int idx = it * 256 + tid;
            int lr = idx >> 6, kc = idx & 63;  // lr 0..15
            int off = (lr * 1024 + kc * 16) ^ ((lr & 7) << 4);
            *(ushort8*)((char*)sWs + off) = *(const ushort8*)(gAttWsT + (size_t)(j * 16 + lr) * 512 + kc * 8);
        }
    } else {
        s_av[tid] = gAv[tid];
        s_av[tid + 256] = gAv[tid + 256];
    }
    __syncthreads();
    for (int t = 0; t < LL; t++) {
        if (bx >= 64) {
            int j = bx - 64;
            // ---- phase A: h_prev @ [Wh | Ws] ----
            if (t > 0) waitflags(gFlagC, 32, (unsigned)t);
            bf16x8 af[16];
            const char* baseA = (t == 0)
                ? ((const char*)gEncHb + (size_t)(63 * BB + arow) * 1024 + aoff)
                : ((const char*)gHcat + (size_t)((t - 1) * BB + arow) * 2048 + aoff);
            ld16(baseA, af);
            f32x4 acc[4], accS;
#pragma unroll
            for (int g = 0; g < 4; g++) acc[g] = (f32x4){0.f, 0.f, 0.f, 0.f};
            accS = (f32x4){0.f, 0.f, 0.f, 0.f};
#pragma unroll
            for (int kk = 0; kk < 16; kk++) {
                int k = kk * 32 + ak;
#pragma unroll
                for (int g = 0; g < 4; g++) {
                    int lr = g * 16 + ar;
                    bf16x8 b = *(const bf16x8*)((char*)sWh + ((lr * 1024 + k * 2) ^ ((lr & 7) << 4)));
                    acc[g] = __builtin_amdgcn_mfma_f32_16x16x32_bf16(af[kk], b, acc[g], 0, 0, 0);
                }
                bf16x8 bs = *(const bf16x8*)((char*)sWs + ((ar * 1024 + k * 2) ^ ((ar & 7) << 4)));
                accS = __builtin_amdgcn_mfma_f32_16x16x32_bf16(af[kk], bs, accS, 0, 0, 0);
            }
#pragma unroll
            for (int ri = 0; ri < 4; ri++)
                stf(gDecT + (size_t)(wid * 16 + rb + ri) * HH + j * 16 + ar, accS[ri]);
            setflag(gFlagA + j, (unsigned)(t + 1));
            // ---- phase C: + ctx @ WxC -> gates -> h ----
            waitflags(gFlagB, 64, (unsigned)(t + 1));
            bf16x8 cf[16];
            ld16((const char*)gHcat + (size_t)(t * BB + arow) * 2048 + 1024 + aoff, cf);
#pragma unroll
            for (int kk = 0; kk < 16; kk++) {
                int k = kk * 32 + ak;
#pragma unroll
                for (int g = 0; g < 4; g++) {
                    int lr = g * 16 + ar;
                    bf16x8 b = *(const bf16x8*)((char*)sWx + ((lr * 1024 + k * 2) ^ ((lr & 7) << 4)));
                    acc[g] = __builtin_amdgcn_mfma_f32_16x16x32_bf16(cf[kk], b, acc[g], 0, 0, 0);
                }
            }
            int hcol = j * 16 + ar;
#pragma unroll
            for (int ri = 0; ri < 4; ri++) {
                int row = wid * 16 + rb + ri;
                int rr = t * BB + row;
                const float* xw = gXWxD + (size_t)rr * G4;
                float zi = acc[0][ri] + xw[hcol];
                float zf = acc[1][ri] + xw[512 + hcol];
                float zg = acc[2][ri] + xw[1024 + hcol];
                float zo = acc[3][ri] + xw[1536 + hcol];
                float co = gC[row * HH + hcol];
                float cn = sigm(zf) * co + sigm(zi) * ftanh(zg);
                float hn = sigm(zo) * ftanh(cn);
                gC[row * HH + hcol] = cn;
                st16b(gHcat + (size_t)rr * 1024 + hcol, f2b(hn));
            }
            setflag(gFlagC + j, (unsigned)(t + 1));
        } else {
            // ---- attention for batch row b ----
            int b = bx;
            waitflags(gFlagA, 32, (unsigned)(t + 1));
            s_dt[tid] = ldf(gDecT + (size_t)b * HH + tid);
            s_dt[tid + 256] = ldf(gDecT + (size_t)b * HH + tid + 256);
            __syncthreads();
            // energy
            int s = tid >> 2, q = tid & 3;
            const float* et = gEncT + (size_t)(b * LL + s) * HH;
            float p = 0.f;
#pragma unroll 4
            for (int i = 0; i < 128; i++) {
                int h = i * 4 + q;
                p += ftanh(et[h] + s_dt[h]) * s_av[h];
            }
            s_red[tid] = p;
            __syncthreads();
            if (tid < 64) {
                float v = s_red[tid * 4] + s_red[tid * 4 + 1] + s_red[tid * 4 + 2] + s_red[tid * 4 + 3];
                float m = v;
                for (int o = 32; o; o >>= 1) m = fmaxf(m, __shfl_xor(m, o));
                float e = __expf(v - m);
                float ss = e;
                for (int o = 32; o; o >>= 1) ss += __shfl_xor(ss, o);
                s_att[tid] = e / ss;
            }
            __syncthreads();
            // context -> ctx half of gHcat (bypass store)
            int c = tid * 2;
            float c0 = 0.f, c1 = 0.f;
            const u16* eh = gEncHb2 + (size_t)b * LL * HH;
#pragma unroll 8
            for (int s2 = 0; s2 < 64; s2++) {
                float a = s_att[s2];
                u32 w = *(const u32*)(eh + (size_t)s2 * HH + c);
                c0 += a * b2f((u16)(w & 0xffff));
                c1 += a * b2f((u16)(w >> 16));
            }
            u32 cw = (u32)f2b(c0) | ((u32)f2b(c1) << 16);
            st32b((u32*)(gHcat + (size_t)(t * BB + b) * 1024 + 512 + c), cw);
            setflag(gFlagB + b, (unsigned)(t + 1));
        }
    }
}

// ---------------- log-softmax in place, online max/sum, float4 ----------------
__global__ __launch_bounds__(256) void k_lsm(float* __restrict__ out) {
    int row = blockIdx.x, tid = threadIdx.x;
    float4* p4 = (float4*)(out + (size_t)row * VT);
    float m = -1e30f, s = 0.f;
    for (int i = tid; i < VT / 4; i += 256) {
        float4 v = p4[i];
        float mx = fmaxf(fmaxf(v.x, v.y), fmaxf(v.z, v.w));
        float mn = fmaxf(m, mx);
        s = s * __expf(m - mn) + __expf(v.x - mn) + __expf(v.y - mn) + __expf(v.z - mn) + __expf(v.w - mn);
        m = mn;
    }
    for (int o = 32; o; o >>= 1) {
        float m2 = __shfl_xor(m, o), s2 = __shfl_xor(s, o);
        float mn = fmaxf(m, m2);
        s = s * __expf(m - mn) + s2 * __expf(m2 - mn);
        m = mn;
    }
    __shared__ float rm[4], rs[4];
    if ((tid & 63) == 0) { rm[tid >> 6] = m; rs[tid >> 6] = s; }
    __syncthreads();
    float mm = fmaxf(fmaxf(rm[0], rm[1]), fmaxf(rm[2], rm[3]));
    float ss = rs[0] * __expf(rm[0] - mm) + rs[1] * __expf(rm[1] - mm) +
               rs[2] * __expf(rm[2] - mm) + rs[3] * __expf(rm[3] - mm);
    float lse = mm + __logf(ss);
    for (int i = tid; i < VT / 4; i += 256) {
        float4 v = p4[i];
        v.x -= lse; v.y -= lse; v.z -= lse; v.w -= lse;
        p4[i] = v;
    }
}

extern "C" void kernel_launch(void* const* d_in, const int* in_sizes, int n_in,
                              void* d_out, int out_size, void* d_ws, size_t ws_size,
                              hipStream_t stream) {
    const int*   src       = (const int*)d_in[0];
    const int*   tgt       = (const int*)d_in[1];
    const float* src_embed = (const float*)d_in[2];
    const float* enc_Wx    = (const float*)d_in[3];
    const float* enc_Wh    = (const float*)d_in[4];
    const float* enc_b     = (const float*)d_in[5];
    const float* tgt_embed = (const float*)d_in[6];
    const float* att_Wh    = (const float*)d_in[7];
    const float* att_Ws    = (const float*)d_in[8];
    const float* att_v     = (const float*)d_in[9];
    const float* dec_Wx    = (const float*)d_in[10];
    const float* dec_Wh    = (const float*)d_in[11];
    const float* dec_b     = (const float*)d_in[12];
    const float* h2o_W     = (const float*)d_in[13];
    const float* h2o_b     = (const float*)d_in[14];
    float* out = (float*)d_out;
    dim3 blk(256);

    k_transpose<<<dim3(VT / 32, 1024 / 32), blk, 0, stream>>>(h2o_W, 1024, VT, 0);
    k_transpose<<<dim3(G4 / 32, EE / 32), blk, 0, stream>>>(enc_Wx, EE, G4, 1);
    k_transpose<<<dim3(G4 / 32, HH / 32), blk, 0, stream>>>(enc_Wh, HH, G4, 2);
    k_transpose<<<dim3(HH / 32, HH / 32), blk, 0, stream>>>(att_Wh, HH, HH, 3);
    k_transpose<<<dim3(G4 / 32, EE / 32), blk, 0, stream>>>(dec_Wx, EE, G4, 4);
    k_transpose<<<dim3(G4 / 32, HH / 32), blk, 0, stream>>>(dec_Wx + (size_t)512 * G4, HH, G4, 5);
    k_transpose<<<dim3(G4 / 32, HH / 32), blk, 0, stream>>>(dec_Wh, HH, G4, 6);
    k_transpose<<<dim3(HH / 32, HH / 32), blk, 0, stream>>>(att_Ws, HH, HH, 7);
    k_gather<<<RT, blk, 0, stream>>>(src, src_embed, 0);
    k_gather<<<RT, blk, 0, stream>>>(tgt, tgt_embed, 1);
    k_zero<<<128, blk, 0, stream>>>();
    // hoisted input GEMMs (+bias folded)
    k_gemm<<<dim3(G4 / 128, RT / 128), blk, 0, stream>>>(0, 512, 0, 512, RT, G4, 512, 2, enc_b, 0);
    k_gemm<<<dim3(G4 / 128, RT / 128), blk, 0, stream>>>(1, 512, 1, 512, RT, G4, 512, 2, dec_b, 1);
    // encoder (cooperative, 32 blocks)
    int dummy = 0;
    void* eargs[] = { &dummy };
    hipLaunchCooperativeKernel((const void*)k_encoder, dim3(32), dim3(256), eargs, 0, stream);
    // enc_t = enc_hiddens @ att_Wh, written b-major [b*64+s][h]
    k_gemm<<<dim3(HH / 128, RT / 128), blk, 0, stream>>>(2, 512, 2, 512, RT, HH, 512, 3, nullptr, 2);
    k_rst<<<1, blk, 0, stream>>>(att_v);
    // decoder (cooperative, 96 blocks)
    hipLaunchCooperativeKernel((const void*)k_decoder, dim3(96), dim3(256), eargs, 0, stream);
    // logits GEMM straight into d_out (+bias, (t,b)->(b,t) remap)
    k_gemm_big<<<(VT / 128) * (RT / 128), blk, 0, stream>>>(h2o_b, out);
    k_lsm<<<RT, blk, 0, stream>>>(out);
}

// Round 8
// 3134.422 us; speedup vs baseline: 2.9456x; 1.1892x over previous
//
#include <hip/hip_runtime.h>
#include <hip/hip_bf16.h>
#include <math.h>

#define BB 64
#define LL 64
#define EE 512
#define HH 512
#define G4 2048
#define VT 32000
#define RT 4096  // LL*BB

typedef unsigned short u16;
typedef unsigned int u32;
typedef __attribute__((ext_vector_type(8))) unsigned short ushort8;
typedef __attribute__((ext_vector_type(8))) short bf16x8;
typedef __attribute__((ext_vector_type(4))) float f32x4;

// ---------------- static device scratch ----------------
__device__ u16   gW2T[(size_t)VT * 1024];   // h2o_W^T (VT x 1024) bf16
__device__ u16   gEncWxT[G4 * EE];
__device__ u16   gEncWhT[G4 * HH];
__device__ u16   gAttWhT[HH * HH];
__device__ u16   gDecWxTe[G4 * EE];
__device__ u16   gDecWxTc[G4 * HH];
__device__ u16   gDecWhT[G4 * HH];
__device__ u16   gWsB[HH * HH];             // att_Ws bf16, ORIGINAL [k][c] layout
__device__ u16   gSrcEmb[RT * EE];
__device__ u16   gTgtEmb[RT * EE];
__device__ float gXWxE[(size_t)RT * G4];    // src_emb @ enc_Wx + enc_b
__device__ float gXWxD[(size_t)RT * G4];    // tgt_emb @ dec_Wx[:512] + dec_b
__device__ u16   gEncHb[(size_t)RT * HH];   // enc h bf16, [t*64+b][h]
__device__ u16   gEncHb2[(size_t)RT * HH];  // enc h bf16, [b*64+t][h]
__device__ u16   gEncTb[(size_t)RT * HH];   // enc_hiddens @ att_Wh, bf16 [b*64+s][h]
__device__ u16   gHcat[(size_t)RT * 1024];  // [h | ctx] bf16, row rr=t*64+b
__device__ float gC[BB * HH];               // LSTM cell state
__device__ float gAv[HH];
__device__ unsigned gFlagE[64];             // encoder: per-block h-ready generation
__device__ unsigned gFlagB[64];             // decoder: ctx ready (64 used)
__device__ unsigned gFlagC[64];             // decoder: h ready (32 used)

__device__ __forceinline__ u16 f2b(float f) {
    union { float f; unsigned u; } v{f};
    unsigned r = v.u + 0x7fffu + ((v.u >> 16) & 1u);
    return (u16)(r >> 16);
}
__device__ __forceinline__ float b2f(u16 x) {
    union { unsigned u; float f; } v; v.u = ((unsigned)x) << 16; return v.f;
}
__device__ __forceinline__ float sigm(float x) { return 1.f / (1.f + __expf(-x)); }
__device__ __forceinline__ float ftanh(float x) {
    x = fminf(15.f, fmaxf(-15.f, x));
    float e = __expf(2.f * x);
    return (e - 1.f) / (e + 1.f);
}

// ---- L2-bypass (MALL-coherent) memory helpers ----
__device__ __forceinline__ void ld16(const void* addr, bf16x8* a) {
    asm volatile(
        "global_load_dwordx4 %0, %16, off sc0 sc1\n\t"
        "global_load_dwordx4 %1, %16, off offset:64 sc0 sc1\n\t"
        "global_load_dwordx4 %2, %16, off offset:128 sc0 sc1\n\t"
        "global_load_dwordx4 %3, %16, off offset:192 sc0 sc1\n\t"
        "global_load_dwordx4 %4, %16, off offset:256 sc0 sc1\n\t"
        "global_load_dwordx4 %5, %16, off offset:320 sc0 sc1\n\t"
        "global_load_dwordx4 %6, %16, off offset:384 sc0 sc1\n\t"
        "global_load_dwordx4 %7, %16, off offset:448 sc0 sc1\n\t"
        "global_load_dwordx4 %8, %16, off offset:512 sc0 sc1\n\t"
        "global_load_dwordx4 %9, %16, off offset:576 sc0 sc1\n\t"
        "global_load_dwordx4 %10, %16, off offset:640 sc0 sc1\n\t"
        "global_load_dwordx4 %11, %16, off offset:704 sc0 sc1\n\t"
        "global_load_dwordx4 %12, %16, off offset:768 sc0 sc1\n\t"
        "global_load_dwordx4 %13, %16, off offset:832 sc0 sc1\n\t"
        "global_load_dwordx4 %14, %16, off offset:896 sc0 sc1\n\t"
        "global_load_dwordx4 %15, %16, off offset:960 sc0 sc1\n\t"
        "s_waitcnt vmcnt(0)"
        : "=&v"(a[0]), "=&v"(a[1]), "=&v"(a[2]), "=&v"(a[3]),
          "=&v"(a[4]), "=&v"(a[5]), "=&v"(a[6]), "=&v"(a[7]),
          "=&v"(a[8]), "=&v"(a[9]), "=&v"(a[10]), "=&v"(a[11]),
          "=&v"(a[12]), "=&v"(a[13]), "=&v"(a[14]), "=&v"(a[15])
        : "v"(addr) : "memory");
}
__device__ __forceinline__ u32 ld1(const void* addr) {
    u32 r;
    asm volatile("global_load_dword %0, %1, off sc0 sc1\n\ts_waitcnt vmcnt(0)"
                 : "=&v"(r) : "v"(addr) : "memory");
    return r;
}
__device__ __forceinline__ void st16b(u16* p, u16 v) {
    u32 vv = v;
    asm volatile("global_store_short %0, %1, off sc0 sc1" :: "v"(p), "v"(vv) : "memory");
}
__device__ __forceinline__ void st32b(u32* p, u32 v) {
    asm volatile("global_store_dword %0, %1, off sc0 sc1" :: "v"(p), "v"(v) : "memory");
}

// set this block's flag after all its data stores have completed at the coherence point
__device__ __forceinline__ void setflag(unsigned* f, unsigned v) {
    asm volatile("s_waitcnt vmcnt(0)" ::: "memory");  // every thread drains its stores
    __syncthreads();
    if (threadIdx.x == 0) st32b((u32*)f, v);
}
// wait until flags[0..n) all >= target (n power of two <= 64); wave 0 polls
__device__ __forceinline__ void waitflags(unsigned* flags, int n, unsigned target) {
    if (threadIdx.x < 64) {
        const unsigned* p = flags + (threadIdx.x & (n - 1));
        for (;;) {
            u32 v = ld1(p);
            if (__all(v >= target)) break;
            __builtin_amdgcn_s_sleep(1);
        }
    }
    __syncthreads();
}

__device__ __forceinline__ void g2l16(const u16* g, u16* l) {
    __builtin_amdgcn_global_load_lds(
        (const __attribute__((address_space(1))) unsigned int*)g,
        (__attribute__((address_space(3))) unsigned int*)l, 16, 0, 0);
}

// ---------------- transpose fp32 (R x C) -> bf16 (C x R) ----------------
__device__ inline u16* bf16sel(int s) {
    switch (s) {
        case 0: return gW2T;    case 1: return gEncWxT; case 2: return gEncWhT;
        case 3: return gAttWhT; case 4: return gDecWxTe; case 5: return gDecWxTc;
        default: return gDecWhT;
    }
}

__global__ __launch_bounds__(256) void k_transpose(const float* __restrict__ in, int R, int C, int sel) {
    __shared__ float tile[32][33];
    int tx = threadIdx.x & 31, ty0 = threadIdx.x >> 5;
    int c0 = blockIdx.x * 32, r0 = blockIdx.y * 32;
#pragma unroll
    for (int k = 0; k < 4; k++) {
        int ty = ty0 + k * 8;
        tile[ty][tx] = in[(size_t)(r0 + ty) * C + c0 + tx];
    }
    __syncthreads();
    u16* out = bf16sel(sel);
#pragma unroll
    for (int k = 0; k < 4; k++) {
        int ty = ty0 + k * 8;
        out[(size_t)(c0 + ty) * R + r0 + tx] = f2b(tile[tx][ty]);
    }
}

__global__ __launch_bounds__(256) void k_tobf(const float* __restrict__ in) {
    int i = blockIdx.x * 256 + threadIdx.x;
    gWsB[i] = f2b(in[i]);
}

__global__ __launch_bounds__(256) void k_gather(const int* __restrict__ tok, const float* __restrict__ tab, int sel) {
    int r = blockIdx.x;
    int b = r & 63, t = r >> 6;
    int token = tok[b * LL + t];
    u16* dst = (sel == 0) ? gSrcEmb : gTgtEmb;
    const float* srow = tab + (size_t)token * EE;
    for (int e = threadIdx.x; e < EE; e += 256)
        dst[(size_t)r * EE + e] = f2b(srow[e]);
}

__global__ __launch_bounds__(256) void k_zero() {
    int i = blockIdx.x * 256 + threadIdx.x;  // 128 blocks
    gC[i] = 0.f;
    if (i < 64) st32b((u32*)(gFlagE + i), 0u);
}

__global__ __launch_bounds__(256) void k_rst(const float* __restrict__ av) {
    int t = threadIdx.x;
    gAv[t] = av[t];
    gAv[t + 256] = av[t + 256];
    if (t < 64) {
        st32b((u32*)(gFlagB + t), 0u);
        st32b((u32*)(gFlagC + t), 0u);
    }
}

// ---------------- generic bf16 MFMA GEMM: C(MxN) = A(MxK) * B^T(NxK) ----------------
// epi 2: fp32 C=v+bias[col]; epi 4: bf16 gEncTb[((row&63)*64+row>>6)*N+col]=v
__global__ __launch_bounds__(256) void k_gemm(int selA, int lda, int selB, int ldb,
                                              int M, int N, int K, int epi,
                                              const float* __restrict__ bias, int selOut) {
    __shared__ u16 sA[128 * 72];
    __shared__ u16 sB[128 * 72];
    const u16* Ag;
    switch (selA) { case 0: Ag = gSrcEmb; break; case 1: Ag = gTgtEmb; break; default: Ag = gEncHb; }
    const u16* Bg;
    switch (selB) { case 0: Bg = gEncWxT; break; case 1: Bg = gDecWxTe; break; default: Bg = gAttWhT; }
    float* Cg = (selOut == 0) ? gXWxE : gXWxD;

    int tid = threadIdx.x, l = tid & 63, wid = tid >> 6, wr = wid >> 1, wc = wid & 1;
    int ar = l & 15, ak = (l >> 4) * 8;
    int rowM = blockIdx.y * 128, colN = blockIdx.x * 128;
    f32x4 acc[4][4];
#pragma unroll
    for (int m = 0; m < 4; m++)
#pragma unroll
        for (int n = 0; n < 4; n++) acc[m][n] = (f32x4){0.f, 0.f, 0.f, 0.f};

    for (int k0 = 0; k0 < K; k0 += 64) {
#pragma unroll
        for (int it = 0; it < 4; it++) {
            int idx = it * 256 + tid;
            int row = idx >> 3, cc = idx & 7;
            *(ushort8*)(sA + row * 72 + cc * 8) =
                *(const ushort8*)(Ag + (size_t)(rowM + row) * lda + k0 + cc * 8);
            *(ushort8*)(sB + row * 72 + cc * 8) =
                *(const ushort8*)(Bg + (size_t)(colN + row) * ldb + k0 + cc * 8);
        }
        __syncthreads();
#pragma unroll
        for (int ks = 0; ks < 2; ks++) {
            bf16x8 a[4], b[4];
#pragma unroll
            for (int m = 0; m < 4; m++) a[m] = *(const bf16x8*)(sA + (wr * 64 + m * 16 + ar) * 72 + ks * 32 + ak);
#pragma unroll
            for (int n = 0; n < 4; n++) b[n] = *(const bf16x8*)(sB + (wc * 64 + n * 16 + ar) * 72 + ks * 32 + ak);
#pragma unroll
            for (int m = 0; m < 4; m++)
#pragma unroll
                for (int n = 0; n < 4; n++)
                    acc[m][n] = __builtin_amdgcn_mfma_f32_16x16x32_bf16(a[m], b[n], acc[m][n], 0, 0, 0);
        }
        __syncthreads();
    }
    int rb = (l >> 4) * 4;
#pragma unroll
    for (int m = 0; m < 4; m++)
#pragma unroll
        for (int n = 0; n < 4; n++)
#pragma unroll
            for (int ri = 0; ri < 4; ri++) {
                int row = rowM + wr * 64 + m * 16 + rb + ri;
                int col = colN + wc * 64 + n * 16 + ar;
                float v = acc[m][n][ri];
                if (epi == 2) Cg[(size_t)row * N + col] = v + bias[col];
                else gEncTb[(size_t)((row & 63) * 64 + (row >> 6)) * N + col] = f2b(v);
            }
}

// ---------------- logits GEMM (m97 structure + XCD swizzle) ----------------
__global__ __launch_bounds__(256) void k_gemm_big(const float* __restrict__ bias, float* __restrict__ out) {
    __shared__ u16 sA[128 * 64];
    __shared__ u16 sB[128 * 64];
    int tid = threadIdx.x, l = tid & 63, wid = tid >> 6, wr = wid >> 1, wc = wid & 1;
    int ar = l & 15, ak = (l >> 4) * 8, rb = (l >> 4) * 4;
    int bid = (blockIdx.x & 7) * 1000 + (blockIdx.x >> 3);  // 8000 blocks, XCD-chunked
    int bxx = bid % (VT / 128), byy = bid / (VT / 128);
    int rowM = byy * 128, colN = bxx * 128;
    f32x4 acc[4][4];
#pragma unroll
    for (int m = 0; m < 4; m++)
#pragma unroll
        for (int n = 0; n < 4; n++) acc[m][n] = (f32x4){0.f, 0.f, 0.f, 0.f};

    int srow = wid * 32 + (l >> 3);
    int scol = (l & 7) * 8;
    for (int k0 = 0; k0 < 1024; k0 += 64) {
#pragma unroll
        for (int c = 0; c < 4; c++) {
            int r = srow + c * 8;
            g2l16(gHcat + (size_t)(rowM + r) * 1024 + k0 + scol, sA + r * 64 + scol);
            g2l16(gW2T + (size_t)(colN + r) * 1024 + k0 + scol, sB + r * 64 + scol);
        }
        __syncthreads();
#pragma unroll
        for (int ks = 0; ks < 2; ks++) {
            bf16x8 a[4], b[4];
#pragma unroll
            for (int m = 0; m < 4; m++) a[m] = *(const bf16x8*)(sA + (wr * 64 + m * 16 + ar) * 64 + ks * 32 + ak);
#pragma unroll
            for (int n = 0; n < 4; n++) b[n] = *(const bf16x8*)(sB + (wc * 64 + n * 16 + ar) * 64 + ks * 32 + ak);
#pragma unroll
            for (int m = 0; m < 4; m++)
#pragma unroll
                for (int n = 0; n < 4; n++)
                    acc[m][n] = __builtin_amdgcn_mfma_f32_16x16x32_bf16(a[m], b[n], acc[m][n], 0, 0, 0);
        }
        __syncthreads();
    }
#pragma unroll
    for (int m = 0; m < 4; m++)
#pragma unroll
        for (int n = 0; n < 4; n++)
#pragma unroll
            for (int ri = 0; ri < 4; ri++) {
                int row = rowM + wr * 64 + m * 16 + rb + ri;
                int col = colN + wc * 64 + n * 16 + ar;
                out[(size_t)((row & 63) * 64 + (row >> 6)) * VT + col] = acc[m][n][ri] + bias[col];
            }
}

// ---------------- encoder: 32 blocks, 16 h-cols each, flag sync ----------------
__global__ __launch_bounds__(256) void k_encoder(int dummy) {
    __shared__ u16 sW[64 * 512];  // 64 rows (g*16+c) x 512 K, XOR-swizzled, 64KB
    int tid = threadIdx.x, l = tid & 63, wid = tid >> 6;
    int j = blockIdx.x;  // h-cols [16j, 16j+16)
#pragma unroll
    for (int it = 0; it < 16; it++) {
        int idx = it * 256 + tid;
        int lr = idx >> 6, kc = idx & 63;
        int gcol = (lr >> 4) * 512 + j * 16 + (lr & 15);
        int off = (lr * 1024 + kc * 16) ^ ((lr & 7) << 4);
        *(ushort8*)((char*)sW + off) = *(const ushort8*)(gEncWhT + (size_t)gcol * 512 + kc * 8);
    }
    __syncthreads();
    int ar = l & 15, ak = (l >> 4) * 8, rb = (l >> 4) * 4;
    int arow = wid * 16 + ar, aoff = (l >> 4) * 16;
    for (int t = 0; t < LL; t++) {
        f32x4 acc[4];
#pragma unroll
        for (int g = 0; g < 4; g++) acc[g] = (f32x4){0.f, 0.f, 0.f, 0.f};
        if (t > 0) {
            waitflags(gFlagE, 32, (unsigned)t);
            bf16x8 af[16];
            ld16((const char*)gEncHb + (size_t)((t - 1) * BB + arow) * 1024 + aoff, af);
#pragma unroll
            for (int kk = 0; kk < 16; kk++) {
                int k = kk * 32 + ak;
#pragma unroll
                for (int g = 0; g < 4; g++) {
                    int lr = g * 16 + ar;
                    bf16x8 b = *(const bf16x8*)((char*)sW + ((lr * 1024 + k * 2) ^ ((lr & 7) << 4)));
                    acc[g] = __builtin_amdgcn_mfma_f32_16x16x32_bf16(af[kk], b, acc[g], 0, 0, 0);
                }
            }
        }
        int hcol = j * 16 + ar;
#pragma unroll
        for (int ri = 0; ri < 4; ri++) {
            int row = wid * 16 + rb + ri;
            int rr = t * BB + row;
            const float* xw = gXWxE + (size_t)rr * G4;
            float zi = acc[0][ri] + xw[hcol];
            float zf = acc[1][ri] + xw[512 + hcol];
            float zg = acc[2][ri] + xw[1024 + hcol];
            float zo = acc[3][ri] + xw[1536 + hcol];
            float co = gC[row * HH + hcol];
            float cn = sigm(zf) * co + sigm(zi) * ftanh(zg);
            float hn = sigm(zo) * ftanh(cn);
            gC[row * HH + hcol] = cn;
            u16 hb = f2b(hn);
            st16b(gEncHb + (size_t)rr * HH + hcol, hb);
            gEncHb2[(size_t)(row * LL + t) * HH + hcol] = hb;  // next-kernel only
        }
        setflag(gFlagE + j, (unsigned)(t + 1));
    }
}

// ---------------- decoder: 96 blocks (64 attn + 32 GEMM), 2 hops/step ----------------
__global__ __launch_bounds__(256) void k_decoder(int dummy) {
    __shared__ u16 sWh[64 * 512];   // dec_Wh slice, 64KB (GEMM blocks)
    __shared__ u16 sWx[64 * 512];   // dec_Wx[512:] slice, 64KB (GEMM blocks)
    __shared__ float s_h[512];
    __shared__ float s_dt[512];
    __shared__ float s_av[512];
    __shared__ float s_att[64];
    __shared__ float s_red[256];
    __shared__ float s_mv[4][520];
    int tid = threadIdx.x, l = tid & 63, wid = tid >> 6;
    int bx = blockIdx.x;
    int ar = l & 15, ak = (l >> 4) * 8, rb = (l >> 4) * 4;
    int arow = wid * 16 + ar, aoff = (l >> 4) * 16;
    if (bx >= 64) {
        int j = bx - 64;  // h-cols [16j, 16j+16)
#pragma unroll
        for (int it = 0; it < 16; it++) {
            int idx = it * 256 + tid;
            int lr = idx >> 6, kc = idx & 63;
            int gcol = (lr >> 4) * 512 + j * 16 + (lr & 15);
            int off = (lr * 1024 + kc * 16) ^ ((lr & 7) << 4);
            *(ushort8*)((char*)sWh + off) = *(const ushort8*)(gDecWhT + (size_t)gcol * 512 + kc * 8);
            *(ushort8*)((char*)sWx + off) = *(const ushort8*)(gDecWxTc + (size_t)gcol * 512 + kc * 8);
        }
    } else {
        s_av[tid] = gAv[tid];
        s_av[tid + 256] = gAv[tid + 256];
    }
    __syncthreads();
    for (int t = 0; t < LL; t++) {
        if (bx >= 64) {
            int j = bx - 64;
            // ---- phase A: zh = h_prev @ Wh_slice (parallel with attention) ----
            if (t > 0) waitflags(gFlagC, 32, (unsigned)t);
            bf16x8 af[16];
            const char* baseA = (t == 0)
                ? ((const char*)gEncHb + (size_t)(63 * BB + arow) * 1024 + aoff)
                : ((const char*)gHcat + (size_t)((t - 1) * BB + arow) * 2048 + aoff);
            ld16(baseA, af);
            f32x4 acc[4];
#pragma unroll
            for (int g = 0; g < 4; g++) acc[g] = (f32x4){0.f, 0.f, 0.f, 0.f};
#pragma unroll
            for (int kk = 0; kk < 16; kk++) {
                int k = kk * 32 + ak;
#pragma unroll
                for (int g = 0; g < 4; g++) {
                    int lr = g * 16 + ar;
                    bf16x8 b = *(const bf16x8*)((char*)sWh + ((lr * 1024 + k * 2) ^ ((lr & 7) << 4)));
                    acc[g] = __builtin_amdgcn_mfma_f32_16x16x32_bf16(af[kk], b, acc[g], 0, 0, 0);
                }
            }
            // ---- phase C: + ctx @ WxC -> gates -> h ----
            waitflags(gFlagB, 64, (unsigned)(t + 1));
            bf16x8 cf[16];
            ld16((const char*)gHcat + (size_t)(t * BB + arow) * 2048 + 1024 + aoff, cf);
#pragma unroll
            for (int kk = 0; kk < 16; kk++) {
                int k = kk * 32 + ak;
#pragma unroll
                for (int g = 0; g < 4; g++) {
                    int lr = g * 16 + ar;
                    bf16x8 b = *(const bf16x8*)((char*)sWx + ((lr * 1024 + k * 2) ^ ((lr & 7) << 4)));
                    acc[g] = __builtin_amdgcn_mfma_f32_16x16x32_bf16(cf[kk], b, acc[g], 0, 0, 0);
                }
            }
            int hcol = j * 16 + ar;
#pragma unroll
            for (int ri = 0; ri < 4; ri++) {
                int row = wid * 16 + rb + ri;
                int rr = t * BB + row;
                const float* xw = gXWxD + (size_t)rr * G4;
                float zi = acc[0][ri] + xw[hcol];
                float zf = acc[1][ri] + xw[512 + hcol];
                float zg = acc[2][ri] + xw[1024 + hcol];
                float zo = acc[3][ri] + xw[1536 + hcol];
                float co = gC[row * HH + hcol];
                float cn = sigm(zf) * co + sigm(zi) * ftanh(zg);
                float hn = sigm(zo) * ftanh(cn);
                gC[row * HH + hcol] = cn;
                st16b(gHcat + (size_t)rr * 1024 + hcol, f2b(hn));
            }
            setflag(gFlagC + j, (unsigned)(t + 1));
        } else {
            // ---- attention for batch row b: decT + energy + softmax + ctx ----
            int b = bx;
            if (t > 0) waitflags(gFlagC, 32, (unsigned)t);  // full h row b
            const char* hb = (t == 0) ? ((const char*)gEncHb + (size_t)(63 * BB + b) * 1024)
                                      : ((const char*)gHcat + (size_t)((t - 1) * BB + b) * 2048);
            u32 hw = ld1(hb + 4 * tid);
            s_h[2 * tid] = b2f((u16)(hw & 0xffff));
            s_h[2 * tid + 1] = b2f((u16)(hw >> 16));
            __syncthreads();
            // decT = h @ att_Ws (Ws read-only, L2/L3-cached, [k][c] layout)
            {
                int c8 = tid & 63, kq = tid >> 6;
                float a8[8];
#pragma unroll
                for (int jj = 0; jj < 8; jj++) a8[jj] = 0.f;
                const u16* wp = gWsB + (size_t)(kq * 128) * 512 + c8 * 8;
#pragma unroll 4
                for (int i = 0; i < 128; i++) {
                    ushort8 w = *(const ushort8*)(wp + (size_t)i * 512);
                    float hk = s_h[kq * 128 + i];
#pragma unroll
                    for (int jj = 0; jj < 8; jj++) a8[jj] += hk * b2f((u16)w[jj]);
                }
#pragma unroll
                for (int jj = 0; jj < 8; jj++) s_mv[kq][c8 * 8 + jj] = a8[jj];
            }
            __syncthreads();
            s_dt[tid] = s_mv[0][tid] + s_mv[1][tid] + s_mv[2][tid] + s_mv[3][tid];
            s_dt[tid + 256] = s_mv[0][tid + 256] + s_mv[1][tid + 256] + s_mv[2][tid + 256] + s_mv[3][tid + 256];
            __syncthreads();
            // energy: thread (s, q): contiguous 128-elem chunk of row s
            {
                int s = tid >> 2, q = tid & 3;
                const u16* et = gEncTb + (size_t)(b * 64 + s) * 512 + q * 128;
                const float* dtp = s_dt + q * 128;
                const float* avp = s_av + q * 128;
                float p = 0.f;
#pragma unroll
                for (int i = 0; i < 16; i++) {
                    ushort8 ev = *(const ushort8*)(et + i * 8);
#pragma unroll
                    for (int jj = 0; jj < 8; jj++) {
                        int h = i * 8 + jj;
                        p += ftanh(b2f((u16)ev[jj]) + dtp[h]) * avp[h];
                    }
                }
                s_red[tid] = p;
            }
            __syncthreads();
            if (tid < 64) {
                float v = s_red[tid * 4] + s_red[tid * 4 + 1] + s_red[tid * 4 + 2] + s_red[tid * 4 + 3];
                float m = v;
                for (int o = 32; o; o >>= 1) m = fmaxf(m, __shfl_xor(m, o));
                float e = __expf(v - m);
                float ss = e;
                for (int o = 32; o; o >>= 1) ss += __shfl_xor(ss, o);
                s_att[tid] = e / ss;
            }
            __syncthreads();
            // context -> ctx half of gHcat (bypass store)
            int c = tid * 2;
            float c0 = 0.f, c1 = 0.f;
            const u16* eh = gEncHb2 + (size_t)b * LL * HH;
#pragma unroll 8
            for (int s2 = 0; s2 < 64; s2++) {
                float a = s_att[s2];
                u32 w = *(const u32*)(eh + (size_t)s2 * HH + c);
                c0 += a * b2f((u16)(w & 0xffff));
                c1 += a * b2f((u16)(w >> 16));
            }
            u32 cw = (u32)f2b(c0) | ((u32)f2b(c1) << 16);
            st32b((u32*)(gHcat + (size_t)(t * BB + b) * 1024 + 512 + c), cw);
            setflag(gFlagB + b, (unsigned)(t + 1));
        }
    }
}

// ---------------- log-softmax in place, online max/sum, float4 ----------------
__global__ __launch_bounds__(256) void k_lsm(float* __restrict__ out) {
    int row = blockIdx.x, tid = threadIdx.x;
    float4* p4 = (float4*)(out + (size_t)row * VT);
    float m = -1e30f, s = 0.f;
    for (int i = tid; i < VT / 4; i += 256) {
        float4 v = p4[i];
        float mx = fmaxf(fmaxf(v.x, v.y), fmaxf(v.z, v.w));
        float mn = fmaxf(m, mx);
        s = s * __expf(m - mn) + __expf(v.x - mn) + __expf(v.y - mn) + __expf(v.z - mn) + __expf(v.w - mn);
        m = mn;
    }
    for (int o = 32; o; o >>= 1) {
        float m2 = __shfl_xor(m, o), s2 = __shfl_xor(s, o);
        float mn = fmaxf(m, m2);
        s = s * __expf(m - mn) + s2 * __expf(m2 - mn);
        m = mn;
    }
    __shared__ float rm[4], rs[4];
    if ((tid & 63) == 0) { rm[tid >> 6] = m; rs[tid >> 6] = s; }
    __syncthreads();
    float mm = fmaxf(fmaxf(rm[0], rm[1]), fmaxf(rm[2], rm[3]));
    float ss = rs[0] * __expf(rm[0] - mm) + rs[1] * __expf(rm[1] - mm) +
               rs[2] * __expf(rm[2] - mm) + rs[3] * __expf(rm[3] - mm);
    float lse = mm + __logf(ss);
    for (int i = tid; i < VT / 4; i += 256) {
        float4 v = p4[i];
        v.x -= lse; v.y -= lse; v.z -= lse; v.w -= lse;
        p4[i] = v;
    }
}

extern "C" void kernel_launch(void* const* d_in, const int* in_sizes, int n_in,
                              void* d_out, int out_size, void* d_ws, size_t ws_size,
                              hipStream_t stream) {
    const int*   src       = (const int*)d_in[0];
    const int*   tgt       = (const int*)d_in[1];
    const float* src_embed = (const float*)d_in[2];
    const float* enc_Wx    = (const float*)d_in[3];
    const float* enc_Wh    = (const float*)d_in[4];
    const float* enc_b     = (const float*)d_in[5];
    const float* tgt_embed = (const float*)d_in[6];
    const float* att_Wh    = (const float*)d_in[7];
    const float* att_Ws    = (const float*)d_in[8];
    const float* att_v     = (const float*)d_in[9];
    const float* dec_Wx    = (const float*)d_in[10];
    const float* dec_Wh    = (const float*)d_in[11];
    const float* dec_b     = (const float*)d_in[12];
    const float* h2o_W     = (const float*)d_in[13];
    const float* h2o_b     = (const float*)d_in[14];
    float* out = (float*)d_out;
    dim3 blk(256);

    k_transpose<<<dim3(VT / 32, 1024 / 32), blk, 0, stream>>>(h2o_W, 1024, VT, 0);
    k_transpose<<<dim3(G4 / 32, EE / 32), blk, 0, stream>>>(enc_Wx, EE, G4, 1);
    k_transpose<<<dim3(G4 / 32, HH / 32), blk, 0, stream>>>(enc_Wh, HH, G4, 2);
    k_transpose<<<dim3(HH / 32, HH / 32), blk, 0, stream>>>(att_Wh, HH, HH, 3);
    k_transpose<<<dim3(G4 / 32, EE / 32), blk, 0, stream>>>(dec_Wx, EE, G4, 4);
    k_transpose<<<dim3(G4 / 32, HH / 32), blk, 0, stream>>>(dec_Wx + (size_t)512 * G4, HH, G4, 5);
    k_transpose<<<dim3(G4 / 32, HH / 32), blk, 0, stream>>>(dec_Wh, HH, G4, 6);
    k_tobf<<<HH * HH / 256, blk, 0, stream>>>(att_Ws);
    k_gather<<<RT, blk, 0, stream>>>(src, src_embed, 0);
    k_gather<<<RT, blk, 0, stream>>>(tgt, tgt_embed, 1);
    k_zero<<<128, blk, 0, stream>>>();
    // hoisted input GEMMs (+bias folded)
    k_gemm<<<dim3(G4 / 128, RT / 128), blk, 0, stream>>>(0, 512, 0, 512, RT, G4, 512, 2, enc_b, 0);
    k_gemm<<<dim3(G4 / 128, RT / 128), blk, 0, stream>>>(1, 512, 1, 512, RT, G4, 512, 2, dec_b, 1);
    // encoder (cooperative, 32 blocks)
    int dummy = 0;
    void* eargs[] = { &dummy };
    hipLaunchCooperativeKernel((const void*)k_encoder, dim3(32), dim3(256), eargs, 0, stream);
    // enc_t = enc_hiddens @ att_Wh -> bf16, b-major [b*64+s][h]
    k_gemm<<<dim3(HH / 128, RT / 128), blk, 0, stream>>>(2, 512, 2, 512, RT, HH, 512, 4, nullptr, 2);
    k_rst<<<1, blk, 0, stream>>>(att_v);
    // decoder (cooperative, 96 blocks)
    hipLaunchCooperativeKernel((const void*)k_decoder, dim3(96), dim3(256), eargs, 0, stream);
    // logits GEMM straight into d_out (+bias, (t,b)->(b,t) remap)
    k_gemm_big<<<(VT / 128) * (RT / 128), blk, 0, stream>>>(h2o_b, out);
    k_lsm<<<RT, blk, 0, stream>>>(out);
}